// Round 10
// baseline (742.564 us; speedup 1.0000x reference)
//
#include <hip/hip_runtime.h>

#define NU 200000
#define NI 200000
#define NN 400000          // NU + NI (unified node space: users 0..NU-1, items NU..NN-1)
#define H 64
#define NE 4000000
#define NP 100000
#define EPSF 1e-5f

#define BSH 9              // nodes per bucket = 512
#define BNODES 512
#define NB ((NN + BNODES - 1) / BNODES)   // 782 buckets
#define CAP 15104          // per-bucket adj capacity (mean padded ~12k, max ~14k)

#define PBLOCKS 512                          // partition blocks
#define EPB ((NE + PBLOCKS - 1) / PBLOCKS)   // 7813 edges per block slice

#define DUMMY 200000       // padded-slot neighbor id -> zeroed row in each table
#define NROW 200002        // table rows per slot (200000 real + zero row + align)

typedef unsigned short u16;
typedef __attribute__((ext_vector_type(8))) short bf16x8;
typedef __attribute__((ext_vector_type(4))) float f32x4;

__device__ __forceinline__ u16 f2bf(float f) {
    unsigned int b = __float_as_uint(f);
    b += 0x7FFFu + ((b >> 16) & 1u);     // round-to-nearest-even
    return (u16)(b >> 16);
}

// ================= CSR build (two-phase, LDS-atomic-only) =================

__global__ __launch_bounds__(256) void part1_kernel(
    const int* __restrict__ src, const int* __restrict__ dst,
    int* __restrict__ blkhist)
{
    __shared__ int hist[NB];
    int tid = threadIdx.x, blk = blockIdx.x;
    for (int i = tid; i < NB; i += 256) hist[i] = 0;
    __syncthreads();
    int e0 = blk * EPB, e1 = min(NE, e0 + EPB);
    for (int e = e0 + tid; e < e1; e += 256) {
        atomicAdd(&hist[src[e] >> BSH], 1);
        atomicAdd(&hist[(NU + dst[e]) >> BSH], 1);
    }
    __syncthreads();
    for (int i = tid; i < NB; i += 256)
        blkhist[(size_t)i * PBLOCKS + blk] = hist[i];
}

__global__ __launch_bounds__(256) void colscan_kernel(
    int* __restrict__ blkhist, int* __restrict__ g_bcnt)
{
    __shared__ int s[256];
    int b = blockIdx.x, tid = threadIdx.x;
    int* col = blkhist + (size_t)b * PBLOCKS;
    int v0 = col[2 * tid], v1 = col[2 * tid + 1];
    int ps = v0 + v1;
    s[tid] = ps;
    __syncthreads();
    for (int d = 1; d < 256; d <<= 1) {
        int t = (tid >= d) ? s[tid - d] : 0;
        __syncthreads();
        s[tid] += t;
        __syncthreads();
    }
    int ex = s[tid] - ps;   // exclusive over pairs
    col[2 * tid] = ex;
    col[2 * tid + 1] = ex + v0;
    if (tid == 255) g_bcnt[b] = s[255];
}

__global__ __launch_bounds__(1024) void bucket_scan_kernel(
    const int* __restrict__ g_bcnt, int* __restrict__ g_boff)
{
    __shared__ int s[1024];
    int tid = threadIdx.x;
    int v = (tid < NB) ? g_bcnt[tid] : 0;
    s[tid] = v;
    __syncthreads();
    for (int d = 1; d < 1024; d <<= 1) {
        int t = (tid >= d) ? s[tid - d] : 0;
        __syncthreads();
        s[tid] += t;
        __syncthreads();
    }
    if (tid < NB) g_boff[tid + 1] = s[tid];
    if (tid == 0) g_boff[0] = 0;
}

// entry = (local_node << 18) | neighbor   (local<512 -> 9 bits, nbr<200000 -> 18 bits)
__global__ __launch_bounds__(256) void part2_kernel(
    const int* __restrict__ src, const int* __restrict__ dst,
    const int* __restrict__ g_boff, const int* __restrict__ blkhist,
    int* __restrict__ staging)
{
    __shared__ int cur[NB];
    int tid = threadIdx.x, blk = blockIdx.x;
    for (int i = tid; i < NB; i += 256)
        cur[i] = g_boff[i] + blkhist[(size_t)i * PBLOCKS + blk];
    __syncthreads();
    int e0 = blk * EPB, e1 = min(NE, e0 + EPB);
    for (int e = e0 + tid; e < e1; e += 256) {
        int s = src[e], d = dst[e];
        int p1 = atomicAdd(&cur[s >> BSH], 1);
        staging[p1] = ((s & (BNODES - 1)) << 18) | d;
        int gn = NU + d;
        int p2 = atomicAdd(&cur[gn >> BSH], 1);
        staging[p2] = ((gn & (BNODES - 1)) << 18) | s;
    }
}

// Per-bucket fill into padded fixed-capacity adj: adj[b*CAP + i].
// Each node's list is padded to a multiple of 8 with DUMMY; real degree -> deg[].
__global__ __launch_bounds__(256) void bucket_fill_kernel(
    const int* __restrict__ g_boff, const int* __restrict__ staging,
    int* __restrict__ off, int* __restrict__ deg, int* __restrict__ adj)
{
    __shared__ int hist[BNODES];     // counts -> padded exclusive offsets (cursors)
    __shared__ int psum[256];
    __shared__ int adj_st[CAP];
    int tid = threadIdx.x;
    int b = blockIdx.x;
    int e0 = g_boff[b], e1 = g_boff[b + 1];
    int cnt = e1 - e0;
    int node_base = b * BNODES;

    for (int i = tid; i < CAP; i += 256) adj_st[i] = DUMMY;   // pad prefill
    hist[tid] = 0; hist[tid + 256] = 0;
    __syncthreads();
    for (int i = tid; i < cnt; i += 256)
        atomicAdd(&hist[staging[e0 + i] >> 18], 1);
    __syncthreads();

    int h0 = hist[2 * tid], h1 = hist[2 * tid + 1];
    int hp0 = (h0 + 7) & ~7, hp1 = (h1 + 7) & ~7;   // padded lengths
    psum[tid] = hp0 + hp1;
    __syncthreads();
    for (int d = 1; d < 256; d <<= 1) {
        int t = (tid >= d) ? psum[tid - d] : 0;
        __syncthreads();
        psum[tid] += t;
        __syncthreads();
    }
    int ex0 = psum[tid] - (hp0 + hp1);
    int ex1 = ex0 + hp0;
    int n0 = node_base + 2 * tid;
    if (n0 < NN)     { off[n0]     = b * CAP + ex0; deg[n0]     = h0; }
    if (n0 + 1 < NN) { off[n0 + 1] = b * CAP + ex1; deg[n0 + 1] = h1; }
    __syncthreads();
    hist[2 * tid] = ex0; hist[2 * tid + 1] = ex1;   // reuse as cursors
    __syncthreads();

    int ptotal = min(psum[255], CAP);   // statistically always < CAP

    for (int i = tid; i < cnt; i += 256) {
        int v = staging[e0 + i];
        int p = atomicAdd(&hist[v >> 18], 1);
        if (p < CAP) adj_st[p] = v & 0x3FFFF;
    }
    __syncthreads();
    for (int i = tid; i < ptotal; i += 256)
        adj[(size_t)b * CAP + i] = adj_st[i];
}

// ================= f32 -> bf16 conversion (both tables, one dispatch) =========
__global__ __launch_bounds__(256) void cvt_kernel(
    const float4* __restrict__ inU, const float4* __restrict__ inI,
    ushort4* __restrict__ outU, ushort4* __restrict__ outI, int n4)
{
    int i = blockIdx.x * 256 + threadIdx.x;
    const float4* in;
    ushort4* out;
    if (i < n4) { in = inU; out = outU; }
    else        { in = inI; out = outI; i -= n4; if (i >= n4) return; }
    float4 v = in[i];
    ushort4 h;
    h.x = f2bf(v.x); h.y = f2bf(v.y); h.z = f2bf(v.z); h.w = f2bf(v.w);
    out[i] = h;
}

// zero the DUMMY row (row 200000) of all 6 feature/agg slots
__global__ __launch_bounds__(256) void zero_pad_kernel(u16* __restrict__ f1)
{
    int tid = threadIdx.x;
    if (tid < 192) {
        int s = tid >> 5, wd = tid & 31;
        unsigned int* p = (unsigned int*)(f1 + (size_t)s * NROW * H + (size_t)DUMMY * H);
        p[wd] = 0u;
    }
}

// ================= pull aggregation (one wave per node, padded lists) ==========
// 16 lanes per row (8 B = 4 feats each), 4 rows per load instruction, no
// branches/masks in the main loop. Final xor-16/32 reduce; lanes 0-15 write.
__global__ __launch_bounds__(256) void pull_kernel(
    const int* __restrict__ off, const int* __restrict__ deg,
    const int* __restrict__ adj,
    const u16* __restrict__ xu16, const u16* __restrict__ xi16,
    u16* __restrict__ agg_u, u16* __restrict__ agg_i)
{
    int wid = (int)((blockIdx.x * 256 + threadIdx.x) >> 6);
    int lane = threadIdx.x & 63;
    if (wid >= NN) return;
    const u16* table;
    u16* out;
    int node;
    if (wid < NU) { node = wid;      table = xi16; out = agg_u; }
    else          { node = wid - NU; table = xu16; out = agg_i; }
    int beg = off[wid];
    int dg  = deg[wid];
    int pdeg = (dg + 7) & ~7;
    int fl = lane & 15;          // feature quad: feats fl*4 .. fl*4+3
    int rg = lane >> 4;          // row group 0..3
    const int* ap = adj + beg + rg;
    float a0 = 0.f, a1 = 0.f, a2 = 0.f, a3 = 0.f;
    for (int k = 0; k < pdeg; k += 8) {
        int id0 = ap[k];
        int id1 = ap[k + 4];
        uint2 w0 = *(const uint2*)&table[(size_t)id0 * H + fl * 4];
        uint2 w1 = *(const uint2*)&table[(size_t)id1 * H + fl * 4];
        a0 += __uint_as_float(w0.x << 16);
        a1 += __uint_as_float(w0.x & 0xFFFF0000u);
        a2 += __uint_as_float(w0.y << 16);
        a3 += __uint_as_float(w0.y & 0xFFFF0000u);
        a0 += __uint_as_float(w1.x << 16);
        a1 += __uint_as_float(w1.x & 0xFFFF0000u);
        a2 += __uint_as_float(w1.y << 16);
        a3 += __uint_as_float(w1.y & 0xFFFF0000u);
    }
    a0 += __shfl_xor(a0, 16); a0 += __shfl_xor(a0, 32);
    a1 += __shfl_xor(a1, 16); a1 += __shfl_xor(a1, 32);
    a2 += __shfl_xor(a2, 16); a2 += __shfl_xor(a2, 32);
    a3 += __shfl_xor(a3, 16); a3 += __shfl_xor(a3, 32);
    if (lane < 16) {
        float inv = 1.0f / fmaxf((float)dg, 1.0f);
        unsigned int lo = ((unsigned int)f2bf(a1 * inv) << 16) | f2bf(a0 * inv);
        unsigned int hi = ((unsigned int)f2bf(a3 * inv) << 16) | f2bf(a2 * inv);
        uint2 pk; pk.x = lo; pk.y = hi;
        *(uint2*)&out[(size_t)node * H + lane * 4] = pk;
    }
}

// ================= MFMA node update (users + items fused) ======================
// out = relu( ([agg | x] @ [Wll;Wlr]) * sc + sh ), all operands bf16, acc f32.
// Block = 4 waves; wave computes a 16-node x 64-feat tile (16 MFMA 16x16x32).
__global__ __launch_bounds__(256) void update_mfma_kernel(
    const u16* __restrict__ aggU, const u16* __restrict__ aggI,
    const u16* __restrict__ xU, const u16* __restrict__ xI,
    u16* __restrict__ outU, u16* __restrict__ outI,
    const u16* __restrict__ wcat,    // this layer: [2 types][64 feat][128 k]
    const float* __restrict__ scsh)  // this layer: [2 types][2][64]
{
    int tid = threadIdx.x;
    bool isU = blockIdx.x < (NU / 64);
    int nb = isU ? blockIdx.x : blockIdx.x - NU / 64;
    const u16* agg = isU ? aggU : aggI;
    const u16* x   = isU ? xU : xI;
    u16* out       = isU ? outU : outI;
    const u16* wt      = wcat + (isU ? 0 : 64 * 128);
    const float* sc_p  = scsh + (isU ? 0 : 128);
    const float* sh_p  = sc_p + 64;

    int wave = tid >> 6, lane = tid & 63;
    int row = lane & 15, g = lane >> 4;
    int node0 = nb * 64 + wave * 16;

    const u16* arow = agg + (size_t)(node0 + row) * H + g * 8;
    const u16* xrow = x   + (size_t)(node0 + row) * H + g * 8;
    bf16x8 a[4];
    a[0] = *(const bf16x8*)(arow);
    a[1] = *(const bf16x8*)(arow + 32);
    a[2] = *(const bf16x8*)(xrow);
    a[3] = *(const bf16x8*)(xrow + 32);

#pragma unroll
    for (int ct = 0; ct < 4; ++ct) {
        int feat = ct * 16 + row;
        const u16* wrow = wt + feat * 128 + g * 8;
        f32x4 acc = {0.f, 0.f, 0.f, 0.f};
#pragma unroll
        for (int kb = 0; kb < 4; ++kb) {
            bf16x8 b = *(const bf16x8*)(wrow + kb * 32);
            acc = __builtin_amdgcn_mfma_f32_16x16x32_bf16(a[kb], b, acc, 0, 0, 0);
        }
        float s = sc_p[feat], h = sh_p[feat];
#pragma unroll
        for (int r = 0; r < 4; ++r) {
            int node = node0 + g * 4 + r;   // D: col=lane&15, row=(lane>>4)*4+r
            float v = fmaxf(acc[r] * s + h, 0.f);
            out[(size_t)node * H + feat] = f2bf(v);
        }
    }
}

// ================= weight prep: stacked transposed bf16 weights + BN fold =====
__global__ __launch_bounds__(256) void wcvt_kernel(
    const float* __restrict__ u_ll_w, const float* __restrict__ u_lr_w,
    const float* __restrict__ i_ll_w, const float* __restrict__ i_lr_w,
    const float* __restrict__ u_ll_b, const float* __restrict__ i_ll_b,
    const float* __restrict__ u_g, const float* __restrict__ u_b,
    const float* __restrict__ u_m, const float* __restrict__ u_v,
    const float* __restrict__ i_g, const float* __restrict__ i_b,
    const float* __restrict__ i_m, const float* __restrict__ i_v,
    u16* __restrict__ wcat, float* __restrict__ scsh)
{
    int idx = blockIdx.x * 256 + threadIdx.x;
    if (idx < 32768) {
        int k = idx & 127, f = (idx >> 7) & 63, t = (idx >> 13) & 1, l = idx >> 14;
        const float* W = t ? (k < 64 ? i_ll_w : i_lr_w)
                           : (k < 64 ? u_ll_w : u_lr_w);
        wcat[idx] = f2bf(W[l * 4096 + (k & 63) * 64 + f]);
    }
    if (idx < 512) {
        int j = idx & 63, half = (idx >> 6) & 1, t = (idx >> 7) & 1, l = idx >> 8;
        const float *g = t ? i_g : u_g, *b = t ? i_b : u_b;
        const float *m = t ? i_m : u_m, *v = t ? i_v : u_v;
        const float *bl = t ? i_ll_b : u_ll_b;
        float sc = g[l * 64 + j] * rsqrtf(v[l * 64 + j] + EPSF);
        scsh[idx] = half ? (bl[l * 64 + j] - m[l * 64 + j]) * sc + b[l * 64 + j]
                         : sc;
    }
}

// ================= MLP head (register-tiled fc1, LDS fc2, bf16 gathers) ========
__global__ __launch_bounds__(256) void mlp_kernel(
    const int* __restrict__ eli,
    const u16* __restrict__ xu16, const u16* __restrict__ xi16,
    const float* __restrict__ fc1w, const float* __restrict__ fc1b,
    const float* __restrict__ fc2w, const float* __restrict__ fc2b,
    float* __restrict__ out, int n)
{
    __shared__ float sW[32][68];
    __shared__ float sA[64][36];
    __shared__ float sH[64][68];
    __shared__ int   sid[128];
    __shared__ float sW2[256];
    int tid = threadIdx.x;
    int p0 = blockIdx.x * 64;
    if (tid < 128) {
        int p = p0 + (tid & 63);
        int side = tid >> 6;
        sid[tid] = (p < n) ? eli[side * NP + p] : -1;
    }
    sW2[tid] = fc2w[tid];
    __syncthreads();

    int jt = (tid & 15) * 4;
    int pt = (tid >> 4) * 4;
    float4 b4 = *(const float4*)&fc1b[jt];
    float acc[4][4];
#pragma unroll
    for (int i = 0; i < 4; ++i) {
        acc[i][0] = b4.x; acc[i][1] = b4.y; acc[i][2] = b4.z; acc[i][3] = b4.w;
    }

    for (int ch = 0; ch < 4; ++ch) {
        int k0 = ch * 32;
        const u16* tab = (ch < 2) ? xu16 : xi16;
        int idbase = (ch < 2) ? 0 : 64;
        int koff = (ch & 1) * 32;
        for (int idx = tid; idx < 64 * 16; idx += 256) {
            int r = idx >> 4, cp = idx & 15;
            int id = sid[idbase + r];
            unsigned int wv = (id >= 0)
                ? *(const unsigned int*)&tab[(size_t)id * H + koff + cp * 2] : 0u;
            sA[r][cp * 2]     = __uint_as_float(wv << 16);
            sA[r][cp * 2 + 1] = __uint_as_float(wv & 0xFFFF0000u);
        }
        for (int idx = tid; idx < 32 * 64; idx += 256) {
            int kk = idx >> 6, j = idx & 63;
            sW[kk][j] = fc1w[(k0 + kk) * 64 + j];
        }
        __syncthreads();
        for (int kk = 0; kk < 32; kk += 4) {
            float a[4][4];
#pragma unroll
            for (int i = 0; i < 4; ++i) {
                float4 t = *(const float4*)&sA[pt + i][kk];
                a[i][0] = t.x; a[i][1] = t.y; a[i][2] = t.z; a[i][3] = t.w;
            }
#pragma unroll
            for (int q = 0; q < 4; ++q) {
                float4 w = *(const float4*)&sW[kk + q][jt];
                float wv[4] = {w.x, w.y, w.z, w.w};
#pragma unroll
                for (int i = 0; i < 4; ++i)
#pragma unroll
                    for (int j = 0; j < 4; ++j)
                        acc[i][j] += a[i][q] * wv[j];
            }
        }
        __syncthreads();
    }

#pragma unroll
    for (int i = 0; i < 4; ++i)
#pragma unroll
        for (int j = 0; j < 4; ++j)
            sH[pt + i][jt + j] = fmaxf(acc[i][j], 0.f);
    __syncthreads();

    int pp = tid >> 2, c = tid & 3;
    float o = 0.f;
#pragma unroll
    for (int j = 0; j < 64; ++j) o += sH[pp][j] * sW2[j * 4 + c];
    int p = p0 + pp;
    if (p < n) out[(size_t)p * 4 + c] = o + fc2b[c];
}

extern "C" void kernel_launch(void* const* d_in, const int* in_sizes, int n_in,
                              void* d_out, int out_size, void* d_ws, size_t ws_size,
                              hipStream_t stream) {
    const int*   edge_index = (const int*)d_in[0];
    const int*   eli        = (const int*)d_in[1];
    const float* user_emb   = (const float*)d_in[2];
    const float* item_emb   = (const float*)d_in[3];
    const float* u_ll_w     = (const float*)d_in[4];
    const float* u_ll_b     = (const float*)d_in[5];
    const float* u_lr_w     = (const float*)d_in[6];
    const float* i_ll_w     = (const float*)d_in[7];
    const float* i_ll_b     = (const float*)d_in[8];
    const float* i_lr_w     = (const float*)d_in[9];
    const float* u_bn_g     = (const float*)d_in[10];
    const float* u_bn_b     = (const float*)d_in[11];
    const float* u_bn_m     = (const float*)d_in[12];
    const float* u_bn_v     = (const float*)d_in[13];
    const float* i_bn_g     = (const float*)d_in[14];
    const float* i_bn_b     = (const float*)d_in[15];
    const float* i_bn_m     = (const float*)d_in[16];
    const float* i_bn_v     = (const float*)d_in[17];
    const float* fc1_w      = (const float*)d_in[18];
    const float* fc1_b      = (const float*)d_in[19];
    const float* fc2_w      = (const float*)d_in[20];
    const float* fc2_b      = (const float*)d_in[21];
    float* out = (float*)d_out;

    const int* src = edge_index;
    const int* dst = edge_index + NE;

    // ---- workspace: 6 slots x 25.6 MB + adj 47.2 MB + off/deg 3.2 MB ≈ 204 MB
    //      (238 MB is the proven-safe ceiling) ----
    const size_t S = (size_t)NROW * H;   // elems per slot (incl. zero row)
    char* w = (char*)d_ws;
    u16* f1 = (u16*)w;          w += 6 * S * 2;
    int* adj    = (int*)w;      w += (size_t)NB * CAP * 4;
    int* off    = (int*)w;      w += (size_t)NN * 4;
    int* deg    = (int*)w;      w += (size_t)NN * 4;
    int* g_bcnt = (int*)w;      w += (size_t)NB * 4;
    int* g_boff = (int*)w;      w += (size_t)(NB + 1) * 4;
    u16* wcat   = (u16*)w;      w += (size_t)32768 * 2;   // [2][2][64][128] bf16
    float* scsh = (float*)w;    w += (size_t)512 * 4;     // [2][2][2][64] f32

    // Slot plan:
    //   s0/s1: emb16_u/i (cvt -> L0 pull + L0 self) -> fin16_u/i (L1 out -> mlp)
    //   s2/s3: staging (32 MB, CSR build)           -> agg16_u/i (both layers)
    //   s4/s5: blkhist (1.6 MB, head of s4)         -> xA16_u/i (L0 out)
    u16* emb16_u = f1 + 0 * S;
    u16* emb16_i = f1 + 1 * S;
    u16* fin16_u = f1 + 0 * S;
    u16* fin16_i = f1 + 1 * S;
    u16* agg16_u = f1 + 2 * S;
    u16* agg16_i = f1 + 3 * S;
    u16* xA16_u  = f1 + 4 * S;
    u16* xA16_i  = f1 + 5 * S;
    int* staging = (int*)(f1 + 2 * S);
    int* blkhist = (int*)(f1 + 4 * S);

    // ---- CSR build (no global atomics, no memsets) ----
    part1_kernel<<<PBLOCKS, 256, 0, stream>>>(src, dst, blkhist);
    colscan_kernel<<<NB, 256, 0, stream>>>(blkhist, g_bcnt);
    bucket_scan_kernel<<<1, 1024, 0, stream>>>(g_bcnt, g_boff);
    part2_kernel<<<PBLOCKS, 256, 0, stream>>>(src, dst, g_boff, blkhist, staging);
    bucket_fill_kernel<<<NB, 256, 0, stream>>>(g_boff, staging, off, deg, adj);

    // ---- bf16 embeddings + zero pad rows + prepped weights ----
    const int n4 = NU * H / 4;
    cvt_kernel<<<(2 * n4 + 255) / 256, 256, 0, stream>>>(
        (const float4*)user_emb, (const float4*)item_emb,
        (ushort4*)emb16_u, (ushort4*)emb16_i, n4);
    zero_pad_kernel<<<1, 256, 0, stream>>>(f1);
    wcvt_kernel<<<128, 256, 0, stream>>>(
        u_ll_w, u_lr_w, i_ll_w, i_lr_w, u_ll_b, i_ll_b,
        u_bn_g, u_bn_b, u_bn_m, u_bn_v,
        i_bn_g, i_bn_b, i_bn_m, i_bn_v, wcat, scsh);

    const int pull_blocks = NN / 4;
    const int upd_blocks = (NU + NI) / 64;

    // ---- layer 0 ----
    pull_kernel<<<pull_blocks, 256, 0, stream>>>(
        off, deg, adj, emb16_u, emb16_i, agg16_u, agg16_i);
    update_mfma_kernel<<<upd_blocks, 256, 0, stream>>>(
        agg16_u, agg16_i, emb16_u, emb16_i, xA16_u, xA16_i,
        wcat, scsh);

    // ---- layer 1 ----
    pull_kernel<<<pull_blocks, 256, 0, stream>>>(
        off, deg, adj, xA16_u, xA16_i, agg16_u, agg16_i);
    update_mfma_kernel<<<upd_blocks, 256, 0, stream>>>(
        agg16_u, agg16_i, xA16_u, xA16_i, fin16_u, fin16_i,
        wcat + 16384, scsh + 256);

    // ---- MLP head ----
    mlp_kernel<<<(NP + 63) / 64, 256, 0, stream>>>(
        eli, fin16_u, fin16_i, fc1_w, fc1_b, fc2_w, fc2_b, out, NP);
}

// Round 11
// 698.515 us; speedup vs baseline: 1.0631x; 1.0631x over previous
//
#include <hip/hip_runtime.h>

#define NU 200000
#define NI 200000
#define NN 400000          // NU + NI (unified node space: users 0..NU-1, items NU..NN-1)
#define H 64
#define NE 4000000
#define NP 100000
#define EPSF 1e-5f

#define BSH 9              // nodes per bucket = 512
#define BNODES 512
#define NB ((NN + BNODES - 1) / BNODES)   // 782 buckets
#define CAP 15104          // per-bucket adj capacity (mean padded ~12k)

#define PBLOCKS 512                          // partition blocks
#define EPB ((NE + PBLOCKS - 1) / PBLOCKS)   // 7813 edges per block slice

#define DUMMY 200000       // padded-slot neighbor id -> zeroed row in each table
#define NROW 200002        // table rows per slot (200000 real + zero row + align)

typedef unsigned short u16;
typedef __attribute__((ext_vector_type(8))) short bf16x8;
typedef __attribute__((ext_vector_type(4))) float f32x4;

__device__ __forceinline__ u16 f2bf(float f) {
    unsigned int b = __float_as_uint(f);
    b += 0x7FFFu + ((b >> 16) & 1u);     // round-to-nearest-even
    return (u16)(b >> 16);
}

// ================= CSR build (two-phase, LDS-atomic-only) =================

__global__ __launch_bounds__(256) void part1_kernel(
    const int* __restrict__ src, const int* __restrict__ dst,
    int* __restrict__ blkhist)
{
    __shared__ int hist[NB];
    int tid = threadIdx.x, blk = blockIdx.x;
    for (int i = tid; i < NB; i += 256) hist[i] = 0;
    __syncthreads();
    int e0 = blk * EPB, e1 = min(NE, e0 + EPB);
    for (int e = e0 + tid; e < e1; e += 256) {
        atomicAdd(&hist[src[e] >> BSH], 1);
        atomicAdd(&hist[(NU + dst[e]) >> BSH], 1);
    }
    __syncthreads();
    for (int i = tid; i < NB; i += 256)
        blkhist[(size_t)i * PBLOCKS + blk] = hist[i];
}

__global__ __launch_bounds__(256) void colscan_kernel(
    int* __restrict__ blkhist, int* __restrict__ g_bcnt)
{
    __shared__ int s[256];
    int b = blockIdx.x, tid = threadIdx.x;
    int* col = blkhist + (size_t)b * PBLOCKS;
    int v0 = col[2 * tid], v1 = col[2 * tid + 1];
    int ps = v0 + v1;
    s[tid] = ps;
    __syncthreads();
    for (int d = 1; d < 256; d <<= 1) {
        int t = (tid >= d) ? s[tid - d] : 0;
        __syncthreads();
        s[tid] += t;
        __syncthreads();
    }
    int ex = s[tid] - ps;   // exclusive over pairs
    col[2 * tid] = ex;
    col[2 * tid + 1] = ex + v0;
    if (tid == 255) g_bcnt[b] = s[255];
}

__global__ __launch_bounds__(1024) void bucket_scan_kernel(
    const int* __restrict__ g_bcnt, int* __restrict__ g_boff)
{
    __shared__ int s[1024];
    int tid = threadIdx.x;
    int v = (tid < NB) ? g_bcnt[tid] : 0;
    s[tid] = v;
    __syncthreads();
    for (int d = 1; d < 1024; d <<= 1) {
        int t = (tid >= d) ? s[tid - d] : 0;
        __syncthreads();
        s[tid] += t;
        __syncthreads();
    }
    if (tid < NB) g_boff[tid + 1] = s[tid];
    if (tid == 0) g_boff[0] = 0;
}

// entry = (local_node << 18) | neighbor   (local<512 -> 9 bits, nbr<200000 -> 18 bits)
__global__ __launch_bounds__(256) void part2_kernel(
    const int* __restrict__ src, const int* __restrict__ dst,
    const int* __restrict__ g_boff, const int* __restrict__ blkhist,
    int* __restrict__ staging)
{
    __shared__ int cur[NB];
    int tid = threadIdx.x, blk = blockIdx.x;
    for (int i = tid; i < NB; i += 256)
        cur[i] = g_boff[i] + blkhist[(size_t)i * PBLOCKS + blk];
    __syncthreads();
    int e0 = blk * EPB, e1 = min(NE, e0 + EPB);
    for (int e = e0 + tid; e < e1; e += 256) {
        int s = src[e], d = dst[e];
        int p1 = atomicAdd(&cur[s >> BSH], 1);
        staging[p1] = ((s & (BNODES - 1)) << 18) | d;
        int gn = NU + d;
        int p2 = atomicAdd(&cur[gn >> BSH], 1);
        staging[p2] = ((gn & (BNODES - 1)) << 18) | s;
    }
}

// Per-bucket fill into padded fixed-capacity adj: adj[b*CAP + i].
// Each node's list is padded to a multiple of 8 with DUMMY; real degree -> deg[].
__global__ __launch_bounds__(256) void bucket_fill_kernel(
    const int* __restrict__ g_boff, const int* __restrict__ staging,
    int* __restrict__ off, int* __restrict__ deg, int* __restrict__ adj)
{
    __shared__ int hist[BNODES];     // counts -> padded exclusive offsets (cursors)
    __shared__ int psum[256];
    __shared__ int adj_st[CAP];
    int tid = threadIdx.x;
    int b = blockIdx.x;
    int e0 = g_boff[b], e1 = g_boff[b + 1];
    int cnt = e1 - e0;
    int node_base = b * BNODES;

    for (int i = tid; i < CAP; i += 256) adj_st[i] = DUMMY;   // pad prefill
    hist[tid] = 0; hist[tid + 256] = 0;
    __syncthreads();
    for (int i = tid; i < cnt; i += 256)
        atomicAdd(&hist[staging[e0 + i] >> 18], 1);
    __syncthreads();

    int h0 = hist[2 * tid], h1 = hist[2 * tid + 1];
    int hp0 = (h0 + 7) & ~7, hp1 = (h1 + 7) & ~7;   // padded lengths
    psum[tid] = hp0 + hp1;
    __syncthreads();
    for (int d = 1; d < 256; d <<= 1) {
        int t = (tid >= d) ? psum[tid - d] : 0;
        __syncthreads();
        psum[tid] += t;
        __syncthreads();
    }
    int ex0 = psum[tid] - (hp0 + hp1);
    int ex1 = ex0 + hp0;
    int n0 = node_base + 2 * tid;
    if (n0 < NN)     { off[n0]     = b * CAP + ex0; deg[n0]     = h0; }
    if (n0 + 1 < NN) { off[n0 + 1] = b * CAP + ex1; deg[n0 + 1] = h1; }
    __syncthreads();
    hist[2 * tid] = ex0; hist[2 * tid + 1] = ex1;   // reuse as cursors
    __syncthreads();

    int ptotal = min(psum[255], CAP);   // statistically always < CAP

    for (int i = tid; i < cnt; i += 256) {
        int v = staging[e0 + i];
        int p = atomicAdd(&hist[v >> 18], 1);
        if (p < CAP) adj_st[p] = v & 0x3FFFF;
    }
    __syncthreads();
    for (int i = tid; i < ptotal; i += 256)
        adj[(size_t)b * CAP + i] = adj_st[i];
}

// ================= f32 -> bf16 conversion (both tables) + zero pad rows =======
__global__ __launch_bounds__(256) void cvt_kernel(
    const float4* __restrict__ inU, const float4* __restrict__ inI,
    ushort4* __restrict__ outU, ushort4* __restrict__ outI,
    u16* __restrict__ f1, int n4)
{
    int tid = threadIdx.x;
    if (blockIdx.x == 0 && tid < 192) {      // zero DUMMY row of all 6 slots
        int s = tid >> 5, wd = tid & 31;
        unsigned int* p = (unsigned int*)(f1 + (size_t)s * NROW * H + (size_t)DUMMY * H);
        p[wd] = 0u;
    }
    int i = blockIdx.x * 256 + tid;
    const float4* in;
    ushort4* out;
    if (i < n4) { in = inU; out = outU; }
    else        { in = inI; out = outI; i -= n4; if (i >= n4) return; }
    float4 v = in[i];
    ushort4 h;
    h.x = f2bf(v.x); h.y = f2bf(v.y); h.z = f2bf(v.z); h.w = f2bf(v.w);
    out[i] = h;
}

// ================= pull aggregation (one wave per node, padded lists) ==========
// Ids preloaded 64-at-a-time (coalesced, register-resident -> full MLP on the
// table gathers). 16 lanes per row (8 B = 4 feats each), 4 rows per load
// instruction, 2 row-groups per step of 8. xor-16/32 reduce; lanes 0-15 write.
__global__ __launch_bounds__(256) void pull_kernel(
    const int* __restrict__ off, const int* __restrict__ deg,
    const int* __restrict__ adj,
    const u16* __restrict__ xu16, const u16* __restrict__ xi16,
    u16* __restrict__ agg_u, u16* __restrict__ agg_i)
{
    int wid = (int)((blockIdx.x * 256 + threadIdx.x) >> 6);
    int lane = threadIdx.x & 63;
    if (wid >= NN) return;
    const u16* table;
    u16* out;
    int node;
    if (wid < NU) { node = wid;      table = xi16; out = agg_u; }
    else          { node = wid - NU; table = xu16; out = agg_i; }
    int beg = off[wid];
    int dg  = deg[wid];
    int pdeg = (dg + 7) & ~7;
    int fl = lane & 15;          // feature quad: feats fl*4 .. fl*4+3
    int rg = lane >> 4;          // row group 0..3
    float a0 = 0.f, a1 = 0.f, a2 = 0.f, a3 = 0.f;
    for (int k0 = 0; k0 < pdeg; k0 += 64) {
        int nb = adj[beg + k0 + lane];        // values past the list are unused
        int nkk = min(64, pdeg - k0);         // multiple of 8
        for (int t = 0; t < nkk; t += 8) {
            int ia = __shfl(nb, t + rg);
            int ib = __shfl(nb, t + 4 + rg);
            uint2 wa = *(const uint2*)&table[(size_t)ia * H + fl * 4];
            uint2 wb = *(const uint2*)&table[(size_t)ib * H + fl * 4];
            a0 += __uint_as_float(wa.x << 16);
            a1 += __uint_as_float(wa.x & 0xFFFF0000u);
            a2 += __uint_as_float(wa.y << 16);
            a3 += __uint_as_float(wa.y & 0xFFFF0000u);
            a0 += __uint_as_float(wb.x << 16);
            a1 += __uint_as_float(wb.x & 0xFFFF0000u);
            a2 += __uint_as_float(wb.y << 16);
            a3 += __uint_as_float(wb.y & 0xFFFF0000u);
        }
    }
    a0 += __shfl_xor(a0, 16); a0 += __shfl_xor(a0, 32);
    a1 += __shfl_xor(a1, 16); a1 += __shfl_xor(a1, 32);
    a2 += __shfl_xor(a2, 16); a2 += __shfl_xor(a2, 32);
    a3 += __shfl_xor(a3, 16); a3 += __shfl_xor(a3, 32);
    if (lane < 16) {
        float inv = 1.0f / fmaxf((float)dg, 1.0f);
        unsigned int lo = ((unsigned int)f2bf(a1 * inv) << 16) | f2bf(a0 * inv);
        unsigned int hi = ((unsigned int)f2bf(a3 * inv) << 16) | f2bf(a2 * inv);
        uint2 pk; pk.x = lo; pk.y = hi;
        *(uint2*)&out[(size_t)node * H + lane * 4] = pk;
    }
}

// ================= MFMA node update (users + items fused) ======================
// out = relu( ([agg | x] @ [Wll;Wlr]) * sc + sh ), all operands bf16, acc f32.
// Block = 4 waves; wave computes a 16-node x 64-feat tile (16 MFMA 16x16x32).
__global__ __launch_bounds__(256) void update_mfma_kernel(
    const u16* __restrict__ aggU, const u16* __restrict__ aggI,
    const u16* __restrict__ xU, const u16* __restrict__ xI,
    u16* __restrict__ outU, u16* __restrict__ outI,
    const u16* __restrict__ wcat,    // this layer: [2 types][64 feat][128 k]
    const float* __restrict__ scsh)  // this layer: [2 types][2][64]
{
    int tid = threadIdx.x;
    bool isU = blockIdx.x < (NU / 64);
    int nb = isU ? blockIdx.x : blockIdx.x - NU / 64;
    const u16* agg = isU ? aggU : aggI;
    const u16* x   = isU ? xU : xI;
    u16* out       = isU ? outU : outI;
    const u16* wt      = wcat + (isU ? 0 : 64 * 128);
    const float* sc_p  = scsh + (isU ? 0 : 128);
    const float* sh_p  = sc_p + 64;

    int wave = tid >> 6, lane = tid & 63;
    int row = lane & 15, g = lane >> 4;
    int node0 = nb * 64 + wave * 16;

    const u16* arow = agg + (size_t)(node0 + row) * H + g * 8;
    const u16* xrow = x   + (size_t)(node0 + row) * H + g * 8;
    bf16x8 a[4];
    a[0] = *(const bf16x8*)(arow);
    a[1] = *(const bf16x8*)(arow + 32);
    a[2] = *(const bf16x8*)(xrow);
    a[3] = *(const bf16x8*)(xrow + 32);

#pragma unroll
    for (int ct = 0; ct < 4; ++ct) {
        int feat = ct * 16 + row;
        const u16* wrow = wt + feat * 128 + g * 8;
        f32x4 acc = {0.f, 0.f, 0.f, 0.f};
#pragma unroll
        for (int kb = 0; kb < 4; ++kb) {
            bf16x8 b = *(const bf16x8*)(wrow + kb * 32);
            acc = __builtin_amdgcn_mfma_f32_16x16x32_bf16(a[kb], b, acc, 0, 0, 0);
        }
        float s = sc_p[feat], h = sh_p[feat];
#pragma unroll
        for (int r = 0; r < 4; ++r) {
            int node = node0 + g * 4 + r;   // D: col=lane&15, row=(lane>>4)*4+r
            float v = fmaxf(acc[r] * s + h, 0.f);
            out[(size_t)node * H + feat] = f2bf(v);
        }
    }
}

// ================= weight prep: stacked transposed bf16 weights + BN fold =====
__global__ __launch_bounds__(256) void wcvt_kernel(
    const float* __restrict__ u_ll_w, const float* __restrict__ u_lr_w,
    const float* __restrict__ i_ll_w, const float* __restrict__ i_lr_w,
    const float* __restrict__ u_ll_b, const float* __restrict__ i_ll_b,
    const float* __restrict__ u_g, const float* __restrict__ u_b,
    const float* __restrict__ u_m, const float* __restrict__ u_v,
    const float* __restrict__ i_g, const float* __restrict__ i_b,
    const float* __restrict__ i_m, const float* __restrict__ i_v,
    u16* __restrict__ wcat, float* __restrict__ scsh)
{
    int idx = blockIdx.x * 256 + threadIdx.x;
    if (idx < 32768) {
        int k = idx & 127, f = (idx >> 7) & 63, t = (idx >> 13) & 1, l = idx >> 14;
        const float* W = t ? (k < 64 ? i_ll_w : i_lr_w)
                           : (k < 64 ? u_ll_w : u_lr_w);
        wcat[idx] = f2bf(W[l * 4096 + (k & 63) * 64 + f]);
    }
    if (idx < 512) {
        int j = idx & 63, half = (idx >> 6) & 1, t = (idx >> 7) & 1, l = idx >> 8;
        const float *g = t ? i_g : u_g, *b = t ? i_b : u_b;
        const float *m = t ? i_m : u_m, *v = t ? i_v : u_v;
        const float *bl = t ? i_ll_b : u_ll_b;
        float sc = g[l * 64 + j] * rsqrtf(v[l * 64 + j] + EPSF);
        scsh[idx] = half ? (bl[l * 64 + j] - m[l * 64 + j]) * sc + b[l * 64 + j]
                         : sc;
    }
}

// ================= MLP head (register-tiled fc1, LDS fc2, bf16 gathers) ========
__global__ __launch_bounds__(256) void mlp_kernel(
    const int* __restrict__ eli,
    const u16* __restrict__ xu16, const u16* __restrict__ xi16,
    const float* __restrict__ fc1w, const float* __restrict__ fc1b,
    const float* __restrict__ fc2w, const float* __restrict__ fc2b,
    float* __restrict__ out, int n)
{
    __shared__ float sW[32][68];
    __shared__ float sA[64][36];
    __shared__ float sH[64][68];
    __shared__ int   sid[128];
    __shared__ float sW2[256];
    int tid = threadIdx.x;
    int p0 = blockIdx.x * 64;
    if (tid < 128) {
        int p = p0 + (tid & 63);
        int side = tid >> 6;
        sid[tid] = (p < n) ? eli[side * NP + p] : -1;
    }
    sW2[tid] = fc2w[tid];
    __syncthreads();

    int jt = (tid & 15) * 4;
    int pt = (tid >> 4) * 4;
    float4 b4 = *(const float4*)&fc1b[jt];
    float acc[4][4];
#pragma unroll
    for (int i = 0; i < 4; ++i) {
        acc[i][0] = b4.x; acc[i][1] = b4.y; acc[i][2] = b4.z; acc[i][3] = b4.w;
    }

    for (int ch = 0; ch < 4; ++ch) {
        int k0 = ch * 32;
        const u16* tab = (ch < 2) ? xu16 : xi16;
        int idbase = (ch < 2) ? 0 : 64;
        int koff = (ch & 1) * 32;
        for (int idx = tid; idx < 64 * 16; idx += 256) {
            int r = idx >> 4, cp = idx & 15;
            int id = sid[idbase + r];
            unsigned int wv = (id >= 0)
                ? *(const unsigned int*)&tab[(size_t)id * H + koff + cp * 2] : 0u;
            sA[r][cp * 2]     = __uint_as_float(wv << 16);
            sA[r][cp * 2 + 1] = __uint_as_float(wv & 0xFFFF0000u);
        }
        for (int idx = tid; idx < 32 * 64; idx += 256) {
            int kk = idx >> 6, j = idx & 63;
            sW[kk][j] = fc1w[(k0 + kk) * 64 + j];
        }
        __syncthreads();
        for (int kk = 0; kk < 32; kk += 4) {
            float a[4][4];
#pragma unroll
            for (int i = 0; i < 4; ++i) {
                float4 t = *(const float4*)&sA[pt + i][kk];
                a[i][0] = t.x; a[i][1] = t.y; a[i][2] = t.z; a[i][3] = t.w;
            }
#pragma unroll
            for (int q = 0; q < 4; ++q) {
                float4 w = *(const float4*)&sW[kk + q][jt];
                float wv[4] = {w.x, w.y, w.z, w.w};
#pragma unroll
                for (int i = 0; i < 4; ++i)
#pragma unroll
                    for (int j = 0; j < 4; ++j)
                        acc[i][j] += a[i][q] * wv[j];
            }
        }
        __syncthreads();
    }

#pragma unroll
    for (int i = 0; i < 4; ++i)
#pragma unroll
        for (int j = 0; j < 4; ++j)
            sH[pt + i][jt + j] = fmaxf(acc[i][j], 0.f);
    __syncthreads();

    int pp = tid >> 2, c = tid & 3;
    float o = 0.f;
#pragma unroll
    for (int j = 0; j < 64; ++j) o += sH[pp][j] * sW2[j * 4 + c];
    int p = p0 + pp;
    if (p < n) out[(size_t)p * 4 + c] = o + fc2b[c];
}

extern "C" void kernel_launch(void* const* d_in, const int* in_sizes, int n_in,
                              void* d_out, int out_size, void* d_ws, size_t ws_size,
                              hipStream_t stream) {
    const int*   edge_index = (const int*)d_in[0];
    const int*   eli        = (const int*)d_in[1];
    const float* user_emb   = (const float*)d_in[2];
    const float* item_emb   = (const float*)d_in[3];
    const float* u_ll_w     = (const float*)d_in[4];
    const float* u_ll_b     = (const float*)d_in[5];
    const float* u_lr_w     = (const float*)d_in[6];
    const float* i_ll_w     = (const float*)d_in[7];
    const float* i_ll_b     = (const float*)d_in[8];
    const float* i_lr_w     = (const float*)d_in[9];
    const float* u_bn_g     = (const float*)d_in[10];
    const float* u_bn_b     = (const float*)d_in[11];
    const float* u_bn_m     = (const float*)d_in[12];
    const float* u_bn_v     = (const float*)d_in[13];
    const float* i_bn_g     = (const float*)d_in[14];
    const float* i_bn_b     = (const float*)d_in[15];
    const float* i_bn_m     = (const float*)d_in[16];
    const float* i_bn_v     = (const float*)d_in[17];
    const float* fc1_w      = (const float*)d_in[18];
    const float* fc1_b      = (const float*)d_in[19];
    const float* fc2_w      = (const float*)d_in[20];
    const float* fc2_b      = (const float*)d_in[21];
    float* out = (float*)d_out;

    const int* src = edge_index;
    const int* dst = edge_index + NE;

    // ---- workspace: 6 slots x 25.6 MB + adj 47.2 MB + off/deg 3.2 MB ≈ 204 MB
    //      (238 MB is the proven-safe ceiling) ----
    const size_t S = (size_t)NROW * H;   // elems per slot (incl. zero row)
    char* w = (char*)d_ws;
    u16* f1 = (u16*)w;          w += 6 * S * 2;
    int* adj    = (int*)w;      w += (size_t)NB * CAP * 4;
    int* off    = (int*)w;      w += (size_t)NN * 4;
    int* deg    = (int*)w;      w += (size_t)NN * 4;
    int* g_bcnt = (int*)w;      w += (size_t)NB * 4;
    int* g_boff = (int*)w;      w += (size_t)(NB + 1) * 4;
    u16* wcat   = (u16*)w;      w += (size_t)32768 * 2;   // [2][2][64][128] bf16
    float* scsh = (float*)w;    w += (size_t)512 * 4;     // [2][2][2][64] f32

    // Slot plan:
    //   s0/s1: emb16_u/i (cvt -> L0 pull + L0 self) -> fin16_u/i (L1 out -> mlp)
    //   s2/s3: staging (32 MB, CSR build)           -> agg16_u/i (both layers)
    //   s4/s5: blkhist (1.6 MB, head of s4)         -> xA16_u/i (L0 out)
    u16* emb16_u = f1 + 0 * S;
    u16* emb16_i = f1 + 1 * S;
    u16* fin16_u = f1 + 0 * S;
    u16* fin16_i = f1 + 1 * S;
    u16* agg16_u = f1 + 2 * S;
    u16* agg16_i = f1 + 3 * S;
    u16* xA16_u  = f1 + 4 * S;
    u16* xA16_i  = f1 + 5 * S;
    int* staging = (int*)(f1 + 2 * S);
    int* blkhist = (int*)(f1 + 4 * S);

    // ---- CSR build (no global atomics, no memsets) ----
    part1_kernel<<<PBLOCKS, 256, 0, stream>>>(src, dst, blkhist);
    colscan_kernel<<<NB, 256, 0, stream>>>(blkhist, g_bcnt);
    bucket_scan_kernel<<<1, 1024, 0, stream>>>(g_bcnt, g_boff);
    part2_kernel<<<PBLOCKS, 256, 0, stream>>>(src, dst, g_boff, blkhist, staging);
    bucket_fill_kernel<<<NB, 256, 0, stream>>>(g_boff, staging, off, deg, adj);

    // ---- bf16 embeddings (+ zero pad rows) + prepped weights ----
    const int n4 = NU * H / 4;
    cvt_kernel<<<(2 * n4 + 255) / 256, 256, 0, stream>>>(
        (const float4*)user_emb, (const float4*)item_emb,
        (ushort4*)emb16_u, (ushort4*)emb16_i, f1, n4);
    wcvt_kernel<<<128, 256, 0, stream>>>(
        u_ll_w, u_lr_w, i_ll_w, i_lr_w, u_ll_b, i_ll_b,
        u_bn_g, u_bn_b, u_bn_m, u_bn_v,
        i_bn_g, i_bn_b, i_bn_m, i_bn_v, wcat, scsh);

    const int pull_blocks = NN / 4;
    const int upd_blocks = (NU + NI) / 64;

    // ---- layer 0 ----
    pull_kernel<<<pull_blocks, 256, 0, stream>>>(
        off, deg, adj, emb16_u, emb16_i, agg16_u, agg16_i);
    update_mfma_kernel<<<upd_blocks, 256, 0, stream>>>(
        agg16_u, agg16_i, emb16_u, emb16_i, xA16_u, xA16_i,
        wcat, scsh);

    // ---- layer 1 ----
    pull_kernel<<<pull_blocks, 256, 0, stream>>>(
        off, deg, adj, xA16_u, xA16_i, agg16_u, agg16_i);
    update_mfma_kernel<<<upd_blocks, 256, 0, stream>>>(
        agg16_u, agg16_i, xA16_u, xA16_i, fin16_u, fin16_i,
        wcat + 16384, scsh + 256);

    // ---- MLP head ----
    mlp_kernel<<<(NP + 63) / 64, 256, 0, stream>>>(
        eli, fin16_u, fin16_i, fc1_w, fc1_b, fc2_w, fc2_b, out, NP);
}

// Round 12
// 645.336 us; speedup vs baseline: 1.1507x; 1.0824x over previous
//
#include <hip/hip_runtime.h>

#define NU 200000
#define NI 200000
#define NN 400000          // NU + NI (unified node space: users 0..NU-1, items NU..NN-1)
#define H 64
#define NE 4000000
#define NP 100000
#define EPSF 1e-5f

#define BSH 9              // nodes per bucket = 512
#define BNODES 512
#define NB ((NN + BNODES - 1) / BNODES)   // 782 buckets
#define CAP 15104          // per-bucket staging/adj capacity (mean 10240, sigma ~101)

#define PBLOCKS 512                          // partition blocks
#define EPB ((NE + PBLOCKS - 1) / PBLOCKS)   // 7813 edges per block slice

#define DUMMY 200000       // padded-slot neighbor id -> zeroed row in each table
#define NROW 200002        // table rows per slot (200000 real + zero row + align)

typedef unsigned short u16;
typedef __attribute__((ext_vector_type(8))) short bf16x8;
typedef __attribute__((ext_vector_type(4))) float f32x4;

__device__ __forceinline__ u16 f2bf(float f) {
    unsigned int b = __float_as_uint(f);
    b += 0x7FFFu + ((b >> 16) & 1u);     // round-to-nearest-even
    return (u16)(b >> 16);
}

// ================= CSR build (two-phase, LDS-atomic-only) =================
// Staging and adj are both fixed-capacity per bucket (b*CAP) -> no global scan.

__global__ __launch_bounds__(256) void part1_kernel(
    const int* __restrict__ src, const int* __restrict__ dst,
    int* __restrict__ blkhist)
{
    __shared__ int hist[NB];
    int tid = threadIdx.x, blk = blockIdx.x;
    for (int i = tid; i < NB; i += 256) hist[i] = 0;
    __syncthreads();
    int e0 = blk * EPB, e1 = min(NE, e0 + EPB);
    for (int e = e0 + tid; e < e1; e += 256) {
        atomicAdd(&hist[src[e] >> BSH], 1);
        atomicAdd(&hist[(NU + dst[e]) >> BSH], 1);
    }
    __syncthreads();
    for (int i = tid; i < NB; i += 256)
        blkhist[(size_t)i * PBLOCKS + blk] = hist[i];
}

// per-bucket exclusive scan over its PBLOCKS counts (in place); totals -> g_bcnt
__global__ __launch_bounds__(256) void colscan_kernel(
    int* __restrict__ blkhist, int* __restrict__ g_bcnt)
{
    __shared__ int s[256];
    int b = blockIdx.x, tid = threadIdx.x;
    int* col = blkhist + (size_t)b * PBLOCKS;
    int v0 = col[2 * tid], v1 = col[2 * tid + 1];
    int ps = v0 + v1;
    s[tid] = ps;
    __syncthreads();
    for (int d = 1; d < 256; d <<= 1) {
        int t = (tid >= d) ? s[tid - d] : 0;
        __syncthreads();
        s[tid] += t;
        __syncthreads();
    }
    int ex = s[tid] - ps;   // exclusive over pairs
    col[2 * tid] = ex;
    col[2 * tid + 1] = ex + v0;
    if (tid == 255) g_bcnt[b] = s[255];
}

// entry = (local_node << 18) | neighbor   (local<512 -> 9 bits, nbr<200000 -> 18 bits)
__global__ __launch_bounds__(256) void part2_kernel(
    const int* __restrict__ src, const int* __restrict__ dst,
    const int* __restrict__ blkhist, int* __restrict__ staging)
{
    __shared__ int cur[NB];
    int tid = threadIdx.x, blk = blockIdx.x;
    for (int i = tid; i < NB; i += 256)
        cur[i] = i * CAP + blkhist[(size_t)i * PBLOCKS + blk];
    __syncthreads();
    int e0 = blk * EPB, e1 = min(NE, e0 + EPB);
    for (int e = e0 + tid; e < e1; e += 256) {
        int s = src[e], d = dst[e];
        int p1 = atomicAdd(&cur[s >> BSH], 1);
        staging[p1] = ((s & (BNODES - 1)) << 18) | d;
        int gn = NU + d;
        int p2 = atomicAdd(&cur[gn >> BSH], 1);
        staging[p2] = ((gn & (BNODES - 1)) << 18) | s;
    }
}

// Per-bucket fill into padded fixed-capacity adj: adj[b*CAP + i].
// Each node's list is padded to a multiple of 8 with DUMMY; real degree -> deg[].
__global__ __launch_bounds__(256) void bucket_fill_kernel(
    const int* __restrict__ g_bcnt, const int* __restrict__ staging,
    int* __restrict__ off, int* __restrict__ deg, int* __restrict__ adj)
{
    __shared__ int hist[BNODES];     // counts -> padded exclusive offsets (cursors)
    __shared__ int psum[256];
    __shared__ int adj_st[CAP];
    int tid = threadIdx.x;
    int b = blockIdx.x;
    int e0 = b * CAP;
    int cnt = g_bcnt[b];
    int node_base = b * BNODES;

    for (int i = tid; i < CAP; i += 256) adj_st[i] = DUMMY;   // pad prefill
    hist[tid] = 0; hist[tid + 256] = 0;
    __syncthreads();
    for (int i = tid; i < cnt; i += 256)
        atomicAdd(&hist[staging[e0 + i] >> 18], 1);
    __syncthreads();

    int h0 = hist[2 * tid], h1 = hist[2 * tid + 1];
    int hp0 = (h0 + 7) & ~7, hp1 = (h1 + 7) & ~7;   // padded lengths
    psum[tid] = hp0 + hp1;
    __syncthreads();
    for (int d = 1; d < 256; d <<= 1) {
        int t = (tid >= d) ? psum[tid - d] : 0;
        __syncthreads();
        psum[tid] += t;
        __syncthreads();
    }
    int ex0 = psum[tid] - (hp0 + hp1);
    int ex1 = ex0 + hp0;
    int n0 = node_base + 2 * tid;
    if (n0 < NN)     { off[n0]     = e0 + ex0; deg[n0]     = h0; }
    if (n0 + 1 < NN) { off[n0 + 1] = e0 + ex1; deg[n0 + 1] = h1; }
    __syncthreads();
    hist[2 * tid] = ex0; hist[2 * tid + 1] = ex1;   // reuse as cursors
    __syncthreads();

    int ptotal = min(psum[255], CAP);   // statistically always < CAP

    for (int i = tid; i < cnt; i += 256) {
        int v = staging[e0 + i];
        int p = atomicAdd(&hist[v >> 18], 1);
        if (p < CAP) adj_st[p] = v & 0x3FFFF;
    }
    __syncthreads();
    for (int i = tid; i < ptotal; i += 256)
        adj[(size_t)b * CAP + i] = adj_st[i];
}

// ================= f32 -> bf16 conversion (both tables) + zero pad rows =======
__global__ __launch_bounds__(256) void cvt_kernel(
    const float4* __restrict__ inU, const float4* __restrict__ inI,
    ushort4* __restrict__ outU, ushort4* __restrict__ outI,
    u16* __restrict__ f1, int n4)
{
    int tid = threadIdx.x;
    if (blockIdx.x == 0 && tid < 192) {      // zero DUMMY row of all 6 slots
        int s = tid >> 5, wd = tid & 31;
        unsigned int* p = (unsigned int*)(f1 + (size_t)s * NROW * H + (size_t)DUMMY * H);
        p[wd] = 0u;
    }
    int i = blockIdx.x * 256 + tid;
    const float4* in;
    ushort4* out;
    if (i < n4) { in = inU; out = outU; }
    else        { in = inI; out = outI; i -= n4; if (i >= n4) return; }
    float4 v = in[i];
    ushort4 h;
    h.x = f2bf(v.x); h.y = f2bf(v.y); h.z = f2bf(v.z); h.w = f2bf(v.w);
    out[i] = h;
}

// ================= fused pull + MFMA update ====================================
// One wave owns 16 nodes: phase 1 aggregates neighbor means into a wave-private
// LDS tile (bf16, [16][72] stride -> benign banking); phase 2 does the 16-node
// x 64-feat MFMA update reading A-frags from that tile. No barriers needed.
// out = relu( ([agg | x] @ [Wll;Wlr]) * sc + sh )
__global__ __launch_bounds__(256) void pull_update_kernel(
    const int* __restrict__ off, const int* __restrict__ deg,
    const int* __restrict__ adj,
    const u16* __restrict__ xu16, const u16* __restrict__ xi16,  // gather tables
    const u16* __restrict__ selfU, const u16* __restrict__ selfI, // self-path rows
    u16* __restrict__ outU, u16* __restrict__ outI,
    const u16* __restrict__ wcat,    // this layer: [2 types][64 feat][128 k]
    const float* __restrict__ scsh)  // this layer: [2 types][2][64]
{
    __shared__ u16 sAgg[4][16][72];
    int tid = threadIdx.x;
    int wave = tid >> 6, lane = tid & 63;
    int gw = blockIdx.x * 4 + wave;            // global wave id, one per 16 nodes
    bool isU = gw < (NU / 16);
    int node0 = (isU ? gw : gw - NU / 16) * 16;
    const u16* table = isU ? xi16 : xu16;      // gather the OPPOSITE type
    const u16* selfx = isU ? selfU : selfI;
    u16* out         = isU ? outU : outI;
    const u16* wt      = wcat + (isU ? 0 : 64 * 128);
    const float* sc_p  = scsh + (isU ? 0 : 128);
    const float* sh_p  = sc_p + 64;
    int wbase = isU ? node0 : NU + node0;      // unified off/deg index

    int offv = 0, degv = 0;
    if (lane < 16) { offv = off[wbase + lane]; degv = deg[wbase + lane]; }

    int fl = lane & 15;          // feature quad: feats fl*4 .. fl*4+3
    int rg = lane >> 4;          // row group 0..3

    // ---- phase 1: 16 sequential node aggregations ----
    for (int s = 0; s < 16; ++s) {
        int beg = __shfl(offv, s);
        int dg  = __shfl(degv, s);
        int pdeg = (dg + 7) & ~7;
        float a0 = 0.f, a1 = 0.f, a2 = 0.f, a3 = 0.f;
        for (int k0 = 0; k0 < pdeg; k0 += 64) {
            int nb = adj[beg + k0 + lane];     // values past the list are unused
            int nkk = min(64, pdeg - k0);      // multiple of 8
            for (int t = 0; t < nkk; t += 8) {
                int ia = __shfl(nb, t + rg);
                int ib = __shfl(nb, t + 4 + rg);
                uint2 wa = *(const uint2*)&table[(size_t)ia * H + fl * 4];
                uint2 wb = *(const uint2*)&table[(size_t)ib * H + fl * 4];
                a0 += __uint_as_float(wa.x << 16);
                a1 += __uint_as_float(wa.x & 0xFFFF0000u);
                a2 += __uint_as_float(wa.y << 16);
                a3 += __uint_as_float(wa.y & 0xFFFF0000u);
                a0 += __uint_as_float(wb.x << 16);
                a1 += __uint_as_float(wb.x & 0xFFFF0000u);
                a2 += __uint_as_float(wb.y << 16);
                a3 += __uint_as_float(wb.y & 0xFFFF0000u);
            }
        }
        a0 += __shfl_xor(a0, 16); a0 += __shfl_xor(a0, 32);
        a1 += __shfl_xor(a1, 16); a1 += __shfl_xor(a1, 32);
        a2 += __shfl_xor(a2, 16); a2 += __shfl_xor(a2, 32);
        a3 += __shfl_xor(a3, 16); a3 += __shfl_xor(a3, 32);
        if (lane < 16) {
            float inv = 1.0f / fmaxf((float)dg, 1.0f);
            unsigned int lo = ((unsigned int)f2bf(a1 * inv) << 16) | f2bf(a0 * inv);
            unsigned int hi = ((unsigned int)f2bf(a3 * inv) << 16) | f2bf(a2 * inv);
            uint2 pk; pk.x = lo; pk.y = hi;
            *(uint2*)&sAgg[wave][s][lane * 4] = pk;
        }
    }
    // no __syncthreads: each wave reads only its own sAgg tile

    // ---- phase 2: MFMA update of the same 16 nodes ----
    int row = lane & 15, g = lane >> 4;
    const u16* xrow = selfx + (size_t)(node0 + row) * H + g * 8;
    bf16x8 a[4];
    a[0] = *(const bf16x8*)&sAgg[wave][row][g * 8];
    a[1] = *(const bf16x8*)&sAgg[wave][row][32 + g * 8];
    a[2] = *(const bf16x8*)(xrow);
    a[3] = *(const bf16x8*)(xrow + 32);

#pragma unroll
    for (int ct = 0; ct < 4; ++ct) {
        int feat = ct * 16 + row;
        const u16* wrow = wt + feat * 128 + g * 8;
        f32x4 acc = {0.f, 0.f, 0.f, 0.f};
#pragma unroll
        for (int kb = 0; kb < 4; ++kb) {
            bf16x8 b = *(const bf16x8*)(wrow + kb * 32);
            acc = __builtin_amdgcn_mfma_f32_16x16x32_bf16(a[kb], b, acc, 0, 0, 0);
        }
        float s = sc_p[feat], h = sh_p[feat];
#pragma unroll
        for (int r = 0; r < 4; ++r) {
            int node = node0 + g * 4 + r;   // D: col=lane&15, row=(lane>>4)*4+r
            float v = fmaxf(acc[r] * s + h, 0.f);
            out[(size_t)node * H + feat] = f2bf(v);
        }
    }
}

// ================= weight prep: stacked transposed bf16 weights + BN fold =====
__global__ __launch_bounds__(256) void wcvt_kernel(
    const float* __restrict__ u_ll_w, const float* __restrict__ u_lr_w,
    const float* __restrict__ i_ll_w, const float* __restrict__ i_lr_w,
    const float* __restrict__ u_ll_b, const float* __restrict__ i_ll_b,
    const float* __restrict__ u_g, const float* __restrict__ u_b,
    const float* __restrict__ u_m, const float* __restrict__ u_v,
    const float* __restrict__ i_g, const float* __restrict__ i_b,
    const float* __restrict__ i_m, const float* __restrict__ i_v,
    u16* __restrict__ wcat, float* __restrict__ scsh)
{
    int idx = blockIdx.x * 256 + threadIdx.x;
    if (idx < 32768) {
        int k = idx & 127, f = (idx >> 7) & 63, t = (idx >> 13) & 1, l = idx >> 14;
        const float* W = t ? (k < 64 ? i_ll_w : i_lr_w)
                           : (k < 64 ? u_ll_w : u_lr_w);
        wcat[idx] = f2bf(W[l * 4096 + (k & 63) * 64 + f]);
    }
    if (idx < 512) {
        int j = idx & 63, half = (idx >> 6) & 1, t = (idx >> 7) & 1, l = idx >> 8;
        const float *g = t ? i_g : u_g, *b = t ? i_b : u_b;
        const float *m = t ? i_m : u_m, *v = t ? i_v : u_v;
        const float *bl = t ? i_ll_b : u_ll_b;
        float sc = g[l * 64 + j] * rsqrtf(v[l * 64 + j] + EPSF);
        scsh[idx] = half ? (bl[l * 64 + j] - m[l * 64 + j]) * sc + b[l * 64 + j]
                         : sc;
    }
}

// ================= MLP head (register-tiled fc1, LDS fc2, bf16 gathers) ========
__global__ __launch_bounds__(256) void mlp_kernel(
    const int* __restrict__ eli,
    const u16* __restrict__ xu16, const u16* __restrict__ xi16,
    const float* __restrict__ fc1w, const float* __restrict__ fc1b,
    const float* __restrict__ fc2w, const float* __restrict__ fc2b,
    float* __restrict__ out, int n)
{
    __shared__ float sW[32][68];
    __shared__ float sA[64][36];
    __shared__ float sH[64][68];
    __shared__ int   sid[128];
    __shared__ float sW2[256];
    int tid = threadIdx.x;
    int p0 = blockIdx.x * 64;
    if (tid < 128) {
        int p = p0 + (tid & 63);
        int side = tid >> 6;
        sid[tid] = (p < n) ? eli[side * NP + p] : -1;
    }
    sW2[tid] = fc2w[tid];
    __syncthreads();

    int jt = (tid & 15) * 4;
    int pt = (tid >> 4) * 4;
    float4 b4 = *(const float4*)&fc1b[jt];
    float acc[4][4];
#pragma unroll
    for (int i = 0; i < 4; ++i) {
        acc[i][0] = b4.x; acc[i][1] = b4.y; acc[i][2] = b4.z; acc[i][3] = b4.w;
    }

    for (int ch = 0; ch < 4; ++ch) {
        int k0 = ch * 32;
        const u16* tab = (ch < 2) ? xu16 : xi16;
        int idbase = (ch < 2) ? 0 : 64;
        int koff = (ch & 1) * 32;
        for (int idx = tid; idx < 64 * 16; idx += 256) {
            int r = idx >> 4, cp = idx & 15;
            int id = sid[idbase + r];
            unsigned int wv = (id >= 0)
                ? *(const unsigned int*)&tab[(size_t)id * H + koff + cp * 2] : 0u;
            sA[r][cp * 2]     = __uint_as_float(wv << 16);
            sA[r][cp * 2 + 1] = __uint_as_float(wv & 0xFFFF0000u);
        }
        for (int idx = tid; idx < 32 * 64; idx += 256) {
            int kk = idx >> 6, j = idx & 63;
            sW[kk][j] = fc1w[(k0 + kk) * 64 + j];
        }
        __syncthreads();
        for (int kk = 0; kk < 32; kk += 4) {
            float a[4][4];
#pragma unroll
            for (int i = 0; i < 4; ++i) {
                float4 t = *(const float4*)&sA[pt + i][kk];
                a[i][0] = t.x; a[i][1] = t.y; a[i][2] = t.z; a[i][3] = t.w;
            }
#pragma unroll
            for (int q = 0; q < 4; ++q) {
                float4 w = *(const float4*)&sW[kk + q][jt];
                float wv[4] = {w.x, w.y, w.z, w.w};
#pragma unroll
                for (int i = 0; i < 4; ++i)
#pragma unroll
                    for (int j = 0; j < 4; ++j)
                        acc[i][j] += a[i][q] * wv[j];
            }
        }
        __syncthreads();
    }

#pragma unroll
    for (int i = 0; i < 4; ++i)
#pragma unroll
        for (int j = 0; j < 4; ++j)
            sH[pt + i][jt + j] = fmaxf(acc[i][j], 0.f);
    __syncthreads();

    int pp = tid >> 2, c = tid & 3;
    float o = 0.f;
#pragma unroll
    for (int j = 0; j < 64; ++j) o += sH[pp][j] * sW2[j * 4 + c];
    int p = p0 + pp;
    if (p < n) out[(size_t)p * 4 + c] = o + fc2b[c];
}

extern "C" void kernel_launch(void* const* d_in, const int* in_sizes, int n_in,
                              void* d_out, int out_size, void* d_ws, size_t ws_size,
                              hipStream_t stream) {
    const int*   edge_index = (const int*)d_in[0];
    const int*   eli        = (const int*)d_in[1];
    const float* user_emb   = (const float*)d_in[2];
    const float* item_emb   = (const float*)d_in[3];
    const float* u_ll_w     = (const float*)d_in[4];
    const float* u_ll_b     = (const float*)d_in[5];
    const float* u_lr_w     = (const float*)d_in[6];
    const float* i_ll_w     = (const float*)d_in[7];
    const float* i_ll_b     = (const float*)d_in[8];
    const float* i_lr_w     = (const float*)d_in[9];
    const float* u_bn_g     = (const float*)d_in[10];
    const float* u_bn_b     = (const float*)d_in[11];
    const float* u_bn_m     = (const float*)d_in[12];
    const float* u_bn_v     = (const float*)d_in[13];
    const float* i_bn_g     = (const float*)d_in[14];
    const float* i_bn_b     = (const float*)d_in[15];
    const float* i_bn_m     = (const float*)d_in[16];
    const float* i_bn_v     = (const float*)d_in[17];
    const float* fc1_w      = (const float*)d_in[18];
    const float* fc1_b      = (const float*)d_in[19];
    const float* fc2_w      = (const float*)d_in[20];
    const float* fc2_b      = (const float*)d_in[21];
    float* out = (float*)d_out;

    const int* src = edge_index;
    const int* dst = edge_index + NE;

    // ---- workspace: 6 slots x 25.6 MB + adj 47.25 MB + off/deg 3.2 MB ≈ 205 MB
    //      (238 MB is the proven-safe ceiling) ----
    const size_t S = (size_t)NROW * H;   // elems per slot (incl. zero row)
    char* w = (char*)d_ws;
    u16* f1 = (u16*)w;          w += 6 * S * 2;
    int* adj    = (int*)w;      w += (size_t)NB * CAP * 4;
    int* off    = (int*)w;      w += (size_t)NN * 4;
    int* deg    = (int*)w;      w += (size_t)NN * 4;
    int* g_bcnt = (int*)w;      w += (size_t)NB * 4;
    u16* wcat   = (u16*)w;      w += (size_t)32768 * 2;   // [2][2][64][128] bf16
    float* scsh = (float*)w;    w += (size_t)512 * 4;     // [2][2][2][64] f32

    // Slot plan:
    //   s0/s1: emb16_u/i (cvt -> L0 gather + self) -> fin16_u/i (L1 out -> mlp)
    //   s2/s3: staging (47.25 MB spans both; CSR build only)
    //   s4   : blkhist (1.6 MB head; dead after part2)
    //   s4/s5: xA16_u/i (L0 out; L1 gather + self)
    u16* emb16_u = f1 + 0 * S;
    u16* emb16_i = f1 + 1 * S;
    u16* fin16_u = f1 + 0 * S;
    u16* fin16_i = f1 + 1 * S;
    u16* xA16_u  = f1 + 4 * S;
    u16* xA16_i  = f1 + 5 * S;
    int* staging = (int*)(f1 + 2 * S);
    int* blkhist = (int*)(f1 + 4 * S);

    // ---- CSR build (no global atomics, no memsets, fixed-capacity buckets) ----
    part1_kernel<<<PBLOCKS, 256, 0, stream>>>(src, dst, blkhist);
    colscan_kernel<<<NB, 256, 0, stream>>>(blkhist, g_bcnt);
    part2_kernel<<<PBLOCKS, 256, 0, stream>>>(src, dst, blkhist, staging);
    bucket_fill_kernel<<<NB, 256, 0, stream>>>(g_bcnt, staging, off, deg, adj);

    // ---- bf16 embeddings (+ zero pad rows) + prepped weights ----
    const int n4 = NU * H / 4;
    cvt_kernel<<<(2 * n4 + 255) / 256, 256, 0, stream>>>(
        (const float4*)user_emb, (const float4*)item_emb,
        (ushort4*)emb16_u, (ushort4*)emb16_i, f1, n4);
    wcvt_kernel<<<128, 256, 0, stream>>>(
        u_ll_w, u_lr_w, i_ll_w, i_lr_w, u_ll_b, i_ll_b,
        u_bn_g, u_bn_b, u_bn_m, u_bn_v,
        i_bn_g, i_bn_b, i_bn_m, i_bn_v, wcat, scsh);

    const int pu_blocks = (NN / 16) / 4;   // one wave per 16 nodes

    // ---- layer 0 (gather + self both from emb16) ----
    pull_update_kernel<<<pu_blocks, 256, 0, stream>>>(
        off, deg, adj, emb16_u, emb16_i, emb16_u, emb16_i,
        xA16_u, xA16_i, wcat, scsh);

    // ---- layer 1 (gather + self both from xA16) ----
    pull_update_kernel<<<pu_blocks, 256, 0, stream>>>(
        off, deg, adj, xA16_u, xA16_i, xA16_u, xA16_i,
        fin16_u, fin16_i, wcat + 16384, scsh + 256);

    // ---- MLP head ----
    mlp_kernel<<<(NP + 63) / 64, 256, 0, stream>>>(
        eli, fin16_u, fin16_i, fc1_w, fc1_b, fc2_w, fc2_b, out, NP);
}

// Round 13
// 550.943 us; speedup vs baseline: 1.3478x; 1.1713x over previous
//
#include <hip/hip_runtime.h>

#define NU 200000
#define NI 200000
#define NN 400000          // NU + NI (unified node space: users 0..NU-1, items NU..NN-1)
#define H 64
#define NE 4000000
#define NP 100000
#define EPSF 1e-5f

#define BSH 9              // nodes per bucket = 512
#define BNODES 512
#define NB ((NN + BNODES - 1) / BNODES)   // 782 buckets
#define CAP 15104          // per-bucket staging/adj capacity (mean 10240, sigma ~101)

#define PBLOCKS 512                          // partition blocks
#define EPB 7816                             // edges per block slice (mult of 8)

#define DUMMY 200000       // padded-slot neighbor id -> zeroed row in each table
#define NROW 200002        // table rows per slot (200000 real + zero row + align)

typedef unsigned short u16;
typedef __attribute__((ext_vector_type(8))) short bf16x8;
typedef __attribute__((ext_vector_type(4))) float f32x4;

__device__ __forceinline__ u16 f2bf(float f) {
    unsigned int b = __float_as_uint(f);
    b += 0x7FFFu + ((b >> 16) & 1u);     // round-to-nearest-even
    return (u16)(b >> 16);
}

// ================= CSR build (two-phase, LDS-atomic-only) =================

__global__ __launch_bounds__(256) void part1_kernel(
    const int* __restrict__ src, const int* __restrict__ dst,
    int* __restrict__ blkhist)
{
    __shared__ int hist[NB];
    int tid = threadIdx.x, blk = blockIdx.x;
    for (int i = tid; i < NB; i += 256) hist[i] = 0;
    __syncthreads();
    int e0 = blk * EPB, e1 = min(NE, e0 + EPB);
    for (int e = e0 + tid * 4; e + 4 <= e1; e += 1024) {
        int4 s4 = *(const int4*)&src[e];
        int4 d4 = *(const int4*)&dst[e];
        atomicAdd(&hist[s4.x >> BSH], 1); atomicAdd(&hist[(NU + d4.x) >> BSH], 1);
        atomicAdd(&hist[s4.y >> BSH], 1); atomicAdd(&hist[(NU + d4.y) >> BSH], 1);
        atomicAdd(&hist[s4.z >> BSH], 1); atomicAdd(&hist[(NU + d4.z) >> BSH], 1);
        atomicAdd(&hist[s4.w >> BSH], 1); atomicAdd(&hist[(NU + d4.w) >> BSH], 1);
    }
    __syncthreads();
    for (int i = tid; i < NB; i += 256)
        blkhist[(size_t)i * PBLOCKS + blk] = hist[i];
}

// per-bucket exclusive scan over its PBLOCKS counts (in place); totals -> g_bcnt
__global__ __launch_bounds__(256) void colscan_kernel(
    int* __restrict__ blkhist, int* __restrict__ g_bcnt)
{
    __shared__ int s[256];
    int b = blockIdx.x, tid = threadIdx.x;
    int* col = blkhist + (size_t)b * PBLOCKS;
    int v0 = col[2 * tid], v1 = col[2 * tid + 1];
    int ps = v0 + v1;
    s[tid] = ps;
    __syncthreads();
    for (int d = 1; d < 256; d <<= 1) {
        int t = (tid >= d) ? s[tid - d] : 0;
        __syncthreads();
        s[tid] += t;
        __syncthreads();
    }
    int ex = s[tid] - ps;   // exclusive over pairs
    col[2 * tid] = ex;
    col[2 * tid + 1] = ex + v0;
    if (tid == 255) g_bcnt[b] = s[255];
}

// entry = (local_node << 18) | neighbor   (local<512 -> 9 bits, nbr<200000 -> 18 bits)
__global__ __launch_bounds__(256) void part2_kernel(
    const int* __restrict__ src, const int* __restrict__ dst,
    const int* __restrict__ blkhist, int* __restrict__ staging)
{
    __shared__ int cur[NB];
    int tid = threadIdx.x, blk = blockIdx.x;
    for (int i = tid; i < NB; i += 256)
        cur[i] = i * CAP + blkhist[(size_t)i * PBLOCKS + blk];
    __syncthreads();
    int e0 = blk * EPB, e1 = min(NE, e0 + EPB);
    for (int e = e0 + tid * 4; e + 4 <= e1; e += 1024) {
        int4 s4 = *(const int4*)&src[e];
        int4 d4 = *(const int4*)&dst[e];
        int sv[4] = {s4.x, s4.y, s4.z, s4.w};
        int dv[4] = {d4.x, d4.y, d4.z, d4.w};
#pragma unroll
        for (int q = 0; q < 4; ++q) {
            int s = sv[q], d = dv[q];
            int p1 = atomicAdd(&cur[s >> BSH], 1);
            staging[p1] = ((s & (BNODES - 1)) << 18) | d;
            int gn = NU + d;
            int p2 = atomicAdd(&cur[gn >> BSH], 1);
            staging[p2] = ((gn & (BNODES - 1)) << 18) | s;
        }
    }
}

// Per-bucket fill into padded fixed-capacity adj: adj[b*CAP + i].
// Each node's list is padded to a multiple of 8 with DUMMY; real degree -> deg[].
__global__ __launch_bounds__(256) void bucket_fill_kernel(
    const int* __restrict__ g_bcnt, const int* __restrict__ staging,
    int* __restrict__ off, int* __restrict__ deg, int* __restrict__ adj)
{
    __shared__ int hist[BNODES];     // counts -> padded exclusive offsets (cursors)
    __shared__ int psum[256];
    __shared__ int adj_st[CAP];
    int tid = threadIdx.x;
    int b = blockIdx.x;
    int e0 = b * CAP;
    int cnt = g_bcnt[b];
    int node_base = b * BNODES;

    for (int i = tid; i < CAP; i += 256) adj_st[i] = DUMMY;   // pad prefill
    hist[tid] = 0; hist[tid + 256] = 0;
    __syncthreads();
    for (int i = tid; i < cnt; i += 256)
        atomicAdd(&hist[staging[e0 + i] >> 18], 1);
    __syncthreads();

    int h0 = hist[2 * tid], h1 = hist[2 * tid + 1];
    int hp0 = (h0 + 7) & ~7, hp1 = (h1 + 7) & ~7;   // padded lengths
    psum[tid] = hp0 + hp1;
    __syncthreads();
    for (int d = 1; d < 256; d <<= 1) {
        int t = (tid >= d) ? psum[tid - d] : 0;
        __syncthreads();
        psum[tid] += t;
        __syncthreads();
    }
    int ex0 = psum[tid] - (hp0 + hp1);
    int ex1 = ex0 + hp0;
    int n0 = node_base + 2 * tid;
    if (n0 < NN)     { off[n0]     = e0 + ex0; deg[n0]     = h0; }
    if (n0 + 1 < NN) { off[n0 + 1] = e0 + ex1; deg[n0 + 1] = h1; }
    __syncthreads();
    hist[2 * tid] = ex0; hist[2 * tid + 1] = ex1;   // reuse as cursors
    __syncthreads();

    int ptotal = min(psum[255], CAP);   // statistically always < CAP

    for (int i = tid; i < cnt; i += 256) {
        int v = staging[e0 + i];
        int p = atomicAdd(&hist[v >> 18], 1);
        if (p < CAP) adj_st[p] = v & 0x3FFFF;
    }
    __syncthreads();
    for (int i = tid; i < ptotal; i += 256)
        adj[(size_t)b * CAP + i] = adj_st[i];
}

// ================= f32 -> bf16 conversion (both tables) + zero pad rows =======
__global__ __launch_bounds__(256) void cvt_kernel(
    const float4* __restrict__ inU, const float4* __restrict__ inI,
    ushort4* __restrict__ outU, ushort4* __restrict__ outI,
    u16* __restrict__ f1, int n4)
{
    int tid = threadIdx.x;
    if (blockIdx.x == 0 && tid < 192) {      // zero DUMMY row of all 6 slots
        int s = tid >> 5, wd = tid & 31;
        unsigned int* p = (unsigned int*)(f1 + (size_t)s * NROW * H + (size_t)DUMMY * H);
        p[wd] = 0u;
    }
    int i = blockIdx.x * 256 + tid;
    const float4* in;
    ushort4* out;
    if (i < n4) { in = inU; out = outU; }
    else        { in = inI; out = outI; i -= n4; if (i >= n4) return; }
    float4 v = in[i];
    ushort4 h;
    h.x = f2bf(v.x); h.y = f2bf(v.y); h.z = f2bf(v.z); h.w = f2bf(v.w);
    out[i] = h;
}

// ================= fused pull + MFMA update ====================================
// One wave owns 16 nodes, processed as 8 PAIRS: lanes 0-31 gather node 2p,
// lanes 32-63 gather node 2p+1 (2 rows x 16 lanes each). 4 independent loads
// per 8-neighbor step + 2-deep software pipeline -> ~8 loads in flight.
// Aggregated means land in a wave-private LDS tile; phase 2 is the 16-node
// x 64-feat MFMA update. No barriers (no cross-wave data flow).
__global__ __launch_bounds__(256) void pull_update_kernel(
    const int* __restrict__ off, const int* __restrict__ deg,
    const int* __restrict__ adj,
    const u16* __restrict__ xu16, const u16* __restrict__ xi16,   // gather tables
    const u16* __restrict__ selfU, const u16* __restrict__ selfI, // self-path rows
    u16* __restrict__ outU, u16* __restrict__ outI,
    const u16* __restrict__ wcat,    // this layer: [2 types][64 feat][128 k]
    const float* __restrict__ scsh)  // this layer: [2 types][2][64]
{
    __shared__ u16 sAgg[4][16][72];
    int tid = threadIdx.x;
    int wave = tid >> 6, lane = tid & 63;
    int gw = blockIdx.x * 4 + wave;            // global wave id, one per 16 nodes
    bool isU = gw < (NU / 16);
    int node0 = (isU ? gw : gw - NU / 16) * 16;
    const u16* table = isU ? xi16 : xu16;      // gather the OPPOSITE type
    const u16* selfx = isU ? selfU : selfI;
    u16* out         = isU ? outU : outI;
    const u16* wt      = wcat + (isU ? 0 : 64 * 128);
    const float* sc_p  = scsh + (isU ? 0 : 128);
    const float* sh_p  = sc_p + 64;
    int wbase = isU ? node0 : NU + node0;      // unified off/deg index

    // hoist self-path loads: in flight during the whole gather phase
    int row = lane & 15, g = lane >> 4;
    const u16* xrow = selfx + (size_t)(node0 + row) * H + g * 8;
    bf16x8 a2 = *(const bf16x8*)(xrow);
    bf16x8 a3 = *(const bf16x8*)(xrow + 32);

    int offv = 0, degv = 0;
    if (lane < 16) { offv = off[wbase + lane]; degv = deg[wbase + lane]; }

    int half = lane >> 5;        // node selector within pair
    int hl   = lane & 31;
    int fl   = hl & 15;          // feature quad: feats fl*4 .. fl*4+3
    int rg   = hl >> 4;          // row group 0..1
    int shb  = (half << 5) + rg; // bpermute base for own node's ids

#define ACC4(w) \
    a0 += __uint_as_float((w).x << 16); a1 += __uint_as_float((w).x & 0xFFFF0000u); \
    a0 += __uint_as_float((w).y << 16); a1 += __uint_as_float((w).y & 0xFFFF0000u);
    // NOTE: replaced below; defined properly per-accumulator

    // ---- phase 1: 8 sequential pair aggregations ----
    for (int p = 0; p < 8; ++p) {
        int begA = __shfl(offv, 2 * p),     dgA = __shfl(degv, 2 * p);
        int begB = __shfl(offv, 2 * p + 1), dgB = __shfl(degv, 2 * p + 1);
        int pdA = (dgA + 7) & ~7, pdB = (dgB + 7) & ~7;
        int myBeg = half ? begB : begA;
        int myPd  = half ? pdB  : pdA;
        int tmax  = max(pdA, pdB);
        float a0 = 0.f, a1 = 0.f, a2f = 0.f, a3f = 0.f;
        for (int k0 = 0; k0 < tmax; k0 += 32) {
            int nb = adj[myBeg + k0 + hl];       // own node's ids, chunk-rel 0..31
            int lim = min(32, tmax - k0);
            // software pipeline, 2 deep, 4 loads per 8-neighbor step
            uint2 c0, c1, c2, c3;
            {
                int i0 = __shfl(nb, shb + 0), i1 = __shfl(nb, shb + 2);
                int i2 = __shfl(nb, shb + 4), i3 = __shfl(nb, shb + 6);
                if (k0 + 0 + rg >= myPd) i0 = DUMMY;
                if (k0 + 2 + rg >= myPd) i1 = DUMMY;
                if (k0 + 4 + rg >= myPd) i2 = DUMMY;
                if (k0 + 6 + rg >= myPd) i3 = DUMMY;
                c0 = *(const uint2*)&table[(size_t)i0 * H + fl * 4];
                c1 = *(const uint2*)&table[(size_t)i1 * H + fl * 4];
                c2 = *(const uint2*)&table[(size_t)i2 * H + fl * 4];
                c3 = *(const uint2*)&table[(size_t)i3 * H + fl * 4];
            }
            for (int tt = 8; tt < lim; tt += 8) {
                int i0 = __shfl(nb, shb + tt + 0), i1 = __shfl(nb, shb + tt + 2);
                int i2 = __shfl(nb, shb + tt + 4), i3 = __shfl(nb, shb + tt + 6);
                if (k0 + tt + 0 + rg >= myPd) i0 = DUMMY;
                if (k0 + tt + 2 + rg >= myPd) i1 = DUMMY;
                if (k0 + tt + 4 + rg >= myPd) i2 = DUMMY;
                if (k0 + tt + 6 + rg >= myPd) i3 = DUMMY;
                uint2 n0 = *(const uint2*)&table[(size_t)i0 * H + fl * 4];
                uint2 n1 = *(const uint2*)&table[(size_t)i1 * H + fl * 4];
                uint2 n2 = *(const uint2*)&table[(size_t)i2 * H + fl * 4];
                uint2 n3 = *(const uint2*)&table[(size_t)i3 * H + fl * 4];
                a0 += __uint_as_float(c0.x << 16); a1 += __uint_as_float(c0.x & 0xFFFF0000u);
                a2f += __uint_as_float(c0.y << 16); a3f += __uint_as_float(c0.y & 0xFFFF0000u);
                a0 += __uint_as_float(c1.x << 16); a1 += __uint_as_float(c1.x & 0xFFFF0000u);
                a2f += __uint_as_float(c1.y << 16); a3f += __uint_as_float(c1.y & 0xFFFF0000u);
                a0 += __uint_as_float(c2.x << 16); a1 += __uint_as_float(c2.x & 0xFFFF0000u);
                a2f += __uint_as_float(c2.y << 16); a3f += __uint_as_float(c2.y & 0xFFFF0000u);
                a0 += __uint_as_float(c3.x << 16); a1 += __uint_as_float(c3.x & 0xFFFF0000u);
                a2f += __uint_as_float(c3.y << 16); a3f += __uint_as_float(c3.y & 0xFFFF0000u);
                c0 = n0; c1 = n1; c2 = n2; c3 = n3;
            }
            a0 += __uint_as_float(c0.x << 16); a1 += __uint_as_float(c0.x & 0xFFFF0000u);
            a2f += __uint_as_float(c0.y << 16); a3f += __uint_as_float(c0.y & 0xFFFF0000u);
            a0 += __uint_as_float(c1.x << 16); a1 += __uint_as_float(c1.x & 0xFFFF0000u);
            a2f += __uint_as_float(c1.y << 16); a3f += __uint_as_float(c1.y & 0xFFFF0000u);
            a0 += __uint_as_float(c2.x << 16); a1 += __uint_as_float(c2.x & 0xFFFF0000u);
            a2f += __uint_as_float(c2.y << 16); a3f += __uint_as_float(c2.y & 0xFFFF0000u);
            a0 += __uint_as_float(c3.x << 16); a1 += __uint_as_float(c3.x & 0xFFFF0000u);
            a2f += __uint_as_float(c3.y << 16); a3f += __uint_as_float(c3.y & 0xFFFF0000u);
        }
        // combine the 2 row-groups of each half
        a0 += __shfl_xor(a0, 16);
        a1 += __shfl_xor(a1, 16);
        a2f += __shfl_xor(a2f, 16);
        a3f += __shfl_xor(a3f, 16);
        int mydg = half ? dgB : dgA;
        if (rg == 0) {   // lanes 0-15 write node 2p; lanes 32-47 write node 2p+1
            float inv = 1.0f / fmaxf((float)mydg, 1.0f);
            unsigned int lo = ((unsigned int)f2bf(a1 * inv) << 16) | f2bf(a0 * inv);
            unsigned int hi = ((unsigned int)f2bf(a3f * inv) << 16) | f2bf(a2f * inv);
            uint2 pk; pk.x = lo; pk.y = hi;
            *(uint2*)&sAgg[wave][2 * p + half][fl * 4] = pk;
        }
    }
#undef ACC4
    // no __syncthreads: each wave reads only its own sAgg tile

    // ---- phase 2: MFMA update of the same 16 nodes ----
    bf16x8 a[4];
    a[0] = *(const bf16x8*)&sAgg[wave][row][g * 8];
    a[1] = *(const bf16x8*)&sAgg[wave][row][32 + g * 8];
    a[2] = a2;
    a[3] = a3;

#pragma unroll
    for (int ct = 0; ct < 4; ++ct) {
        int feat = ct * 16 + row;
        const u16* wrow = wt + feat * 128 + g * 8;
        f32x4 acc = {0.f, 0.f, 0.f, 0.f};
#pragma unroll
        for (int kb = 0; kb < 4; ++kb) {
            bf16x8 b = *(const bf16x8*)(wrow + kb * 32);
            acc = __builtin_amdgcn_mfma_f32_16x16x32_bf16(a[kb], b, acc, 0, 0, 0);
        }
        float s = sc_p[feat], h = sh_p[feat];
#pragma unroll
        for (int r = 0; r < 4; ++r) {
            int node = node0 + g * 4 + r;   // D: col=lane&15, row=(lane>>4)*4+r
            float v = fmaxf(acc[r] * s + h, 0.f);
            out[(size_t)node * H + feat] = f2bf(v);
        }
    }
}

// ================= weight prep: stacked transposed bf16 weights + BN fold =====
__global__ __launch_bounds__(256) void wcvt_kernel(
    const float* __restrict__ u_ll_w, const float* __restrict__ u_lr_w,
    const float* __restrict__ i_ll_w, const float* __restrict__ i_lr_w,
    const float* __restrict__ u_ll_b, const float* __restrict__ i_ll_b,
    const float* __restrict__ u_g, const float* __restrict__ u_b,
    const float* __restrict__ u_m, const float* __restrict__ u_v,
    const float* __restrict__ i_g, const float* __restrict__ i_b,
    const float* __restrict__ i_m, const float* __restrict__ i_v,
    u16* __restrict__ wcat, float* __restrict__ scsh)
{
    int idx = blockIdx.x * 256 + threadIdx.x;
    if (idx < 32768) {
        int k = idx & 127, f = (idx >> 7) & 63, t = (idx >> 13) & 1, l = idx >> 14;
        const float* W = t ? (k < 64 ? i_ll_w : i_lr_w)
                           : (k < 64 ? u_ll_w : u_lr_w);
        wcat[idx] = f2bf(W[l * 4096 + (k & 63) * 64 + f]);
    }
    if (idx < 512) {
        int j = idx & 63, half = (idx >> 6) & 1, t = (idx >> 7) & 1, l = idx >> 8;
        const float *g = t ? i_g : u_g, *b = t ? i_b : u_b;
        const float *m = t ? i_m : u_m, *v = t ? i_v : u_v;
        const float *bl = t ? i_ll_b : u_ll_b;
        float sc = g[l * 64 + j] * rsqrtf(v[l * 64 + j] + EPSF);
        scsh[idx] = half ? (bl[l * 64 + j] - m[l * 64 + j]) * sc + b[l * 64 + j]
                         : sc;
    }
}

// ================= MLP head (register-tiled fc1, LDS fc2, bf16 gathers) ========
__global__ __launch_bounds__(256) void mlp_kernel(
    const int* __restrict__ eli,
    const u16* __restrict__ xu16, const u16* __restrict__ xi16,
    const float* __restrict__ fc1w, const float* __restrict__ fc1b,
    const float* __restrict__ fc2w, const float* __restrict__ fc2b,
    float* __restrict__ out, int n)
{
    __shared__ float sW[32][68];
    __shared__ float sA[64][36];
    __shared__ float sH[64][68];
    __shared__ int   sid[128];
    __shared__ float sW2[256];
    int tid = threadIdx.x;
    int p0 = blockIdx.x * 64;
    if (tid < 128) {
        int p = p0 + (tid & 63);
        int side = tid >> 6;
        sid[tid] = (p < n) ? eli[side * NP + p] : -1;
    }
    sW2[tid] = fc2w[tid];
    __syncthreads();

    int jt = (tid & 15) * 4;
    int pt = (tid >> 4) * 4;
    float4 b4 = *(const float4*)&fc1b[jt];
    float acc[4][4];
#pragma unroll
    for (int i = 0; i < 4; ++i) {
        acc[i][0] = b4.x; acc[i][1] = b4.y; acc[i][2] = b4.z; acc[i][3] = b4.w;
    }

    for (int ch = 0; ch < 4; ++ch) {
        int k0 = ch * 32;
        const u16* tab = (ch < 2) ? xu16 : xi16;
        int idbase = (ch < 2) ? 0 : 64;
        int koff = (ch & 1) * 32;
        for (int idx = tid; idx < 64 * 16; idx += 256) {
            int r = idx >> 4, cp = idx & 15;
            int id = sid[idbase + r];
            unsigned int wv = (id >= 0)
                ? *(const unsigned int*)&tab[(size_t)id * H + koff + cp * 2] : 0u;
            sA[r][cp * 2]     = __uint_as_float(wv << 16);
            sA[r][cp * 2 + 1] = __uint_as_float(wv & 0xFFFF0000u);
        }
        for (int idx = tid; idx < 32 * 64; idx += 256) {
            int kk = idx >> 6, j = idx & 63;
            sW[kk][j] = fc1w[(k0 + kk) * 64 + j];
        }
        __syncthreads();
        for (int kk = 0; kk < 32; kk += 4) {
            float a[4][4];
#pragma unroll
            for (int i = 0; i < 4; ++i) {
                float4 t = *(const float4*)&sA[pt + i][kk];
                a[i][0] = t.x; a[i][1] = t.y; a[i][2] = t.z; a[i][3] = t.w;
            }
#pragma unroll
            for (int q = 0; q < 4; ++q) {
                float4 w = *(const float4*)&sW[kk + q][jt];
                float wv[4] = {w.x, w.y, w.z, w.w};
#pragma unroll
                for (int i = 0; i < 4; ++i)
#pragma unroll
                    for (int j = 0; j < 4; ++j)
                        acc[i][j] += a[i][q] * wv[j];
            }
        }
        __syncthreads();
    }

#pragma unroll
    for (int i = 0; i < 4; ++i)
#pragma unroll
        for (int j = 0; j < 4; ++j)
            sH[pt + i][jt + j] = fmaxf(acc[i][j], 0.f);
    __syncthreads();

    int pp = tid >> 2, c = tid & 3;
    float o = 0.f;
#pragma unroll
    for (int j = 0; j < 64; ++j) o += sH[pp][j] * sW2[j * 4 + c];
    int p = p0 + pp;
    if (p < n) out[(size_t)p * 4 + c] = o + fc2b[c];
}

extern "C" void kernel_launch(void* const* d_in, const int* in_sizes, int n_in,
                              void* d_out, int out_size, void* d_ws, size_t ws_size,
                              hipStream_t stream) {
    const int*   edge_index = (const int*)d_in[0];
    const int*   eli        = (const int*)d_in[1];
    const float* user_emb   = (const float*)d_in[2];
    const float* item_emb   = (const float*)d_in[3];
    const float* u_ll_w     = (const float*)d_in[4];
    const float* u_ll_b     = (const float*)d_in[5];
    const float* u_lr_w     = (const float*)d_in[6];
    const float* i_ll_w     = (const float*)d_in[7];
    const float* i_ll_b     = (const float*)d_in[8];
    const float* i_lr_w     = (const float*)d_in[9];
    const float* u_bn_g     = (const float*)d_in[10];
    const float* u_bn_b     = (const float*)d_in[11];
    const float* u_bn_m     = (const float*)d_in[12];
    const float* u_bn_v     = (const float*)d_in[13];
    const float* i_bn_g     = (const float*)d_in[14];
    const float* i_bn_b     = (const float*)d_in[15];
    const float* i_bn_m     = (const float*)d_in[16];
    const float* i_bn_v     = (const float*)d_in[17];
    const float* fc1_w      = (const float*)d_in[18];
    const float* fc1_b      = (const float*)d_in[19];
    const float* fc2_w      = (const float*)d_in[20];
    const float* fc2_b      = (const float*)d_in[21];
    float* out = (float*)d_out;

    const int* src = edge_index;
    const int* dst = edge_index + NE;

    // ---- workspace: 6 slots x 25.6 MB + adj 47.25 MB + off/deg 3.2 MB ≈ 205 MB
    //      (238 MB is the proven-safe ceiling) ----
    const size_t S = (size_t)NROW * H;   // elems per slot (incl. zero row)
    char* w = (char*)d_ws;
    u16* f1 = (u16*)w;          w += 6 * S * 2;
    int* adj    = (int*)w;      w += ((size_t)NB * CAP + 128) * 4;  // +128 overread pad
    int* off    = (int*)w;      w += (size_t)NN * 4;
    int* deg    = (int*)w;      w += (size_t)NN * 4;
    int* g_bcnt = (int*)w;      w += (size_t)NB * 4;
    u16* wcat   = (u16*)w;      w += (size_t)32768 * 2;   // [2][2][64][128] bf16
    float* scsh = (float*)w;    w += (size_t)512 * 4;     // [2][2][2][64] f32

    // Slot plan:
    //   s0/s1: emb16_u/i (cvt -> L0 gather + self) -> fin16_u/i (L1 out -> mlp)
    //   s2/s3: staging (47.25 MB spans both; CSR build only)
    //   s4   : blkhist (1.6 MB head; dead after part2)
    //   s4/s5: xA16_u/i (L0 out; L1 gather + self)
    u16* emb16_u = f1 + 0 * S;
    u16* emb16_i = f1 + 1 * S;
    u16* fin16_u = f1 + 0 * S;
    u16* fin16_i = f1 + 1 * S;
    u16* xA16_u  = f1 + 4 * S;
    u16* xA16_i  = f1 + 5 * S;
    int* staging = (int*)(f1 + 2 * S);
    int* blkhist = (int*)(f1 + 4 * S);

    // ---- CSR build (no global atomics, no memsets, fixed-capacity buckets) ----
    part1_kernel<<<PBLOCKS, 256, 0, stream>>>(src, dst, blkhist);
    colscan_kernel<<<NB, 256, 0, stream>>>(blkhist, g_bcnt);
    part2_kernel<<<PBLOCKS, 256, 0, stream>>>(src, dst, blkhist, staging);
    bucket_fill_kernel<<<NB, 256, 0, stream>>>(g_bcnt, staging, off, deg, adj);

    // ---- bf16 embeddings (+ zero pad rows) + prepped weights ----
    const int n4 = NU * H / 4;
    cvt_kernel<<<(2 * n4 + 255) / 256, 256, 0, stream>>>(
        (const float4*)user_emb, (const float4*)item_emb,
        (ushort4*)emb16_u, (ushort4*)emb16_i, f1, n4);
    wcvt_kernel<<<128, 256, 0, stream>>>(
        u_ll_w, u_lr_w, i_ll_w, i_lr_w, u_ll_b, i_ll_b,
        u_bn_g, u_bn_b, u_bn_m, u_bn_v,
        i_bn_g, i_bn_b, i_bn_m, i_bn_v, wcat, scsh);

    const int pu_blocks = (NN / 16) / 4;   // one wave per 16 nodes

    // ---- layer 0 (gather + self both from emb16) ----
    pull_update_kernel<<<pu_blocks, 256, 0, stream>>>(
        off, deg, adj, emb16_u, emb16_i, emb16_u, emb16_i,
        xA16_u, xA16_i, wcat, scsh);

    // ---- layer 1 (gather + self both from xA16) ----
    pull_update_kernel<<<pu_blocks, 256, 0, stream>>>(
        off, deg, adj, xA16_u, xA16_i, xA16_u, xA16_i,
        fin16_u, fin16_i, wcat + 16384, scsh + 256);

    // ---- MLP head ----
    mlp_kernel<<<(NP + 63) / 64, 256, 0, stream>>>(
        eli, fin16_u, fin16_i, fc1_w, fc1_b, fc2_w, fc2_b, out, NP);
}

// Round 14
// 544.953 us; speedup vs baseline: 1.3626x; 1.0110x over previous
//
#include <hip/hip_runtime.h>

#define NU 200000
#define NI 200000
#define NN 400000          // NU + NI (unified node space: users 0..NU-1, items NU..NN-1)
#define H 64
#define NE 4000000
#define NP 100000
#define EPSF 1e-5f

#define BSH 9              // nodes per bucket = 512
#define BNODES 512
#define NB ((NN + BNODES - 1) / BNODES)   // 782 buckets
#define CAP 15104          // per-bucket staging/adj capacity (padded mean ~13.3k, ~15 sigma slack)

#define PBLOCKS 512                          // partition blocks
#define EPB 7816                             // edges per block slice (mult of 8)

#define DUMMY 200000       // padded-slot neighbor id -> zeroed row in each table
#define NROW 200002        // table rows per slot (200000 real + zero row + align)

#define CVTB ((2 * (NU * H / 4) + 255) / 256)   // 25000 cvt blocks
#define WCVTB 128                                // wcvt blocks

typedef unsigned short u16;
typedef __attribute__((ext_vector_type(8))) short bf16x8;
typedef __attribute__((ext_vector_type(4))) float f32x4;

__device__ __forceinline__ u16 f2bf(float f) {
    unsigned int b = __float_as_uint(f);
    b += 0x7FFFu + ((b >> 16) & 1u);     // round-to-nearest-even
    return (u16)(b >> 16);
}

// ================= prep: part1 histogram + bf16 cvt + weight prep (one dispatch)
__global__ __launch_bounds__(256) void prep_kernel(
    const int* __restrict__ src, const int* __restrict__ dst,
    int* __restrict__ blkhist,
    const float4* __restrict__ inU, const float4* __restrict__ inI,
    ushort4* __restrict__ outU, ushort4* __restrict__ outI,
    u16* __restrict__ f1,
    const float* __restrict__ u_ll_w, const float* __restrict__ u_lr_w,
    const float* __restrict__ i_ll_w, const float* __restrict__ i_lr_w,
    const float* __restrict__ u_ll_b, const float* __restrict__ i_ll_b,
    const float* __restrict__ u_g, const float* __restrict__ u_b,
    const float* __restrict__ u_m, const float* __restrict__ u_v,
    const float* __restrict__ i_g, const float* __restrict__ i_b,
    const float* __restrict__ i_m, const float* __restrict__ i_v,
    u16* __restrict__ wcat, float* __restrict__ scsh)
{
    int bid = blockIdx.x, tid = threadIdx.x;
    if (bid < PBLOCKS) {
        // ---- part1: per-(bucket, block) entry counts ----
        __shared__ int hist[NB];
        for (int i = tid; i < NB; i += 256) hist[i] = 0;
        __syncthreads();
        int e0 = bid * EPB, e1 = min(NE, e0 + EPB);
        for (int e = e0 + tid * 4; e + 4 <= e1; e += 1024) {
            int4 s4 = *(const int4*)&src[e];
            int4 d4 = *(const int4*)&dst[e];
            atomicAdd(&hist[s4.x >> BSH], 1); atomicAdd(&hist[(NU + d4.x) >> BSH], 1);
            atomicAdd(&hist[s4.y >> BSH], 1); atomicAdd(&hist[(NU + d4.y) >> BSH], 1);
            atomicAdd(&hist[s4.z >> BSH], 1); atomicAdd(&hist[(NU + d4.z) >> BSH], 1);
            atomicAdd(&hist[s4.w >> BSH], 1); atomicAdd(&hist[(NU + d4.w) >> BSH], 1);
        }
        __syncthreads();
        for (int i = tid; i < NB; i += 256)
            blkhist[(size_t)i * PBLOCKS + bid] = hist[i];
    } else if (bid < PBLOCKS + CVTB) {
        // ---- cvt: f32 -> bf16 tables; block 0 also zeroes DUMMY rows 0,1,4,5 ----
        int cb = bid - PBLOCKS;
        if (cb == 0 && tid < 128) {
            const int sl[4] = {0, 1, 4, 5};
            int s = sl[tid >> 5], wd = tid & 31;
            unsigned int* p = (unsigned int*)(f1 + (size_t)s * NROW * H + (size_t)DUMMY * H);
            p[wd] = 0u;
        }
        const int n4 = NU * H / 4;
        int i = cb * 256 + tid;
        const float4* in;
        ushort4* out;
        if (i < n4) { in = inU; out = outU; }
        else        { in = inI; out = outI; i -= n4; if (i >= n4) return; }
        float4 v = in[i];
        ushort4 h;
        h.x = f2bf(v.x); h.y = f2bf(v.y); h.z = f2bf(v.z); h.w = f2bf(v.w);
        out[i] = h;
    } else {
        // ---- wcvt: stacked transposed bf16 weights + BN fold ----
        int idx = (bid - PBLOCKS - CVTB) * 256 + tid;
        if (idx < 32768) {
            int k = idx & 127, f = (idx >> 7) & 63, t = (idx >> 13) & 1, l = idx >> 14;
            const float* W = t ? (k < 64 ? i_ll_w : i_lr_w)
                               : (k < 64 ? u_ll_w : u_lr_w);
            wcat[idx] = f2bf(W[l * 4096 + (k & 63) * 64 + f]);
        }
        if (idx < 512) {
            int j = idx & 63, half = (idx >> 6) & 1, t = (idx >> 7) & 1, l = idx >> 8;
            const float *g = t ? i_g : u_g, *b = t ? i_b : u_b;
            const float *m = t ? i_m : u_m, *v = t ? i_v : u_v;
            const float *bl = t ? i_ll_b : u_ll_b;
            float sc = g[l * 64 + j] * rsqrtf(v[l * 64 + j] + EPSF);
            scsh[idx] = half ? (bl[l * 64 + j] - m[l * 64 + j]) * sc + b[l * 64 + j]
                             : sc;
        }
    }
}

// per-bucket exclusive scan over its PBLOCKS counts (in place); totals -> g_bcnt
__global__ __launch_bounds__(256) void colscan_kernel(
    int* __restrict__ blkhist, int* __restrict__ g_bcnt)
{
    __shared__ int s[256];
    int b = blockIdx.x, tid = threadIdx.x;
    int* col = blkhist + (size_t)b * PBLOCKS;
    int v0 = col[2 * tid], v1 = col[2 * tid + 1];
    int ps = v0 + v1;
    s[tid] = ps;
    __syncthreads();
    for (int d = 1; d < 256; d <<= 1) {
        int t = (tid >= d) ? s[tid - d] : 0;
        __syncthreads();
        s[tid] += t;
        __syncthreads();
    }
    int ex = s[tid] - ps;   // exclusive over pairs
    col[2 * tid] = ex;
    col[2 * tid + 1] = ex + v0;
    if (tid == 255) g_bcnt[b] = s[255];
}

// entry = (local_node << 18) | neighbor   (local<512 -> 9 bits, nbr<200000 -> 18 bits)
__global__ __launch_bounds__(256) void part2_kernel(
    const int* __restrict__ src, const int* __restrict__ dst,
    const int* __restrict__ blkhist, int* __restrict__ staging)
{
    __shared__ int cur[NB];
    int tid = threadIdx.x, blk = blockIdx.x;
    for (int i = tid; i < NB; i += 256)
        cur[i] = i * CAP + blkhist[(size_t)i * PBLOCKS + blk];
    __syncthreads();
    int e0 = blk * EPB, e1 = min(NE, e0 + EPB);
    for (int e = e0 + tid * 4; e + 4 <= e1; e += 1024) {
        int4 s4 = *(const int4*)&src[e];
        int4 d4 = *(const int4*)&dst[e];
        int sv[4] = {s4.x, s4.y, s4.z, s4.w};
        int dv[4] = {d4.x, d4.y, d4.z, d4.w};
#pragma unroll
        for (int q = 0; q < 4; ++q) {
            int s = sv[q], d = dv[q];
            int p1 = atomicAdd(&cur[s >> BSH], 1);
            staging[p1] = ((s & (BNODES - 1)) << 18) | d;
            int gn = NU + d;
            int p2 = atomicAdd(&cur[gn >> BSH], 1);
            staging[p2] = ((gn & (BNODES - 1)) << 18) | s;
        }
    }
}

// Per-bucket fill into pair-max-padded fixed-capacity adj: adj[b*CAP + i].
// Nodes (2t, 2t+1) are padded to the SAME 8-multiple length (max of the two);
// adj holds BYTE offsets (id*128) into the 128-B-row tables; pads -> DUMMY<<7.
__global__ __launch_bounds__(256) void bucket_fill_kernel(
    const int* __restrict__ g_bcnt, const int* __restrict__ staging,
    int* __restrict__ off, int* __restrict__ deg, int* __restrict__ adj)
{
    __shared__ int hist[BNODES];     // counts -> exclusive slot offsets (cursors)
    __shared__ int psum[256];
    __shared__ int adj_st[CAP];
    int tid = threadIdx.x;
    int b = blockIdx.x;
    int e0 = b * CAP;
    int cnt = g_bcnt[b];
    int node_base = b * BNODES;

    for (int i = tid; i < CAP; i += 256) adj_st[i] = DUMMY << 7;   // pad prefill
    hist[tid] = 0; hist[tid + 256] = 0;
    __syncthreads();
    for (int i = tid; i < cnt; i += 256)
        atomicAdd(&hist[staging[e0 + i] >> 18], 1);
    __syncthreads();

    int h0 = hist[2 * tid], h1 = hist[2 * tid + 1];
    int hp = max((h0 + 7) & ~7, (h1 + 7) & ~7);   // pair-max padded length
    psum[tid] = 2 * hp;
    __syncthreads();
    for (int d = 1; d < 256; d <<= 1) {
        int t = (tid >= d) ? psum[tid - d] : 0;
        __syncthreads();
        psum[tid] += t;
        __syncthreads();
    }
    int ex0 = psum[tid] - 2 * hp;
    int ex1 = ex0 + hp;
    int n0 = node_base + 2 * tid;
    if (n0 < NN)     { off[n0]     = e0 + ex0; deg[n0]     = h0; }
    if (n0 + 1 < NN) { off[n0 + 1] = e0 + ex1; deg[n0 + 1] = h1; }
    __syncthreads();
    hist[2 * tid] = ex0; hist[2 * tid + 1] = ex1;   // reuse as cursors
    __syncthreads();

    int ptotal = min(psum[255], CAP);   // statistically always < CAP

    for (int i = tid; i < cnt; i += 256) {
        int v = staging[e0 + i];
        int p = atomicAdd(&hist[v >> 18], 1);
        if (p < CAP) adj_st[p] = (v & 0x3FFFF) << 7;   // byte offset
    }
    __syncthreads();
    for (int i = tid; i < ptotal; i += 256)
        adj[(size_t)b * CAP + i] = adj_st[i];
}

// ================= fused pull + MFMA update ====================================
// One wave owns 16 nodes as 8 PAIRS: lanes 0-31 gather node 2p, lanes 32-63
// node 2p+1 (2 rows x 16 lanes). Pair-max padding -> no per-load clamps; adj
// holds byte offsets -> saddr loads. 2-deep pipeline, 4 loads per step.
__global__ __launch_bounds__(256) void pull_update_kernel(
    const int* __restrict__ off, const int* __restrict__ deg,
    const int* __restrict__ adj,
    const u16* __restrict__ xu16, const u16* __restrict__ xi16,   // gather tables
    const u16* __restrict__ selfU, const u16* __restrict__ selfI, // self-path rows
    u16* __restrict__ outU, u16* __restrict__ outI,
    const u16* __restrict__ wcat,    // this layer: [2 types][64 feat][128 k]
    const float* __restrict__ scsh)  // this layer: [2 types][2][64]
{
    __shared__ u16 sAgg[4][16][72];
    int tid = threadIdx.x;
    int wave = tid >> 6, lane = tid & 63;
    int gw = blockIdx.x * 4 + wave;            // global wave id, one per 16 nodes
    bool isU = gw < (NU / 16);
    int node0 = (isU ? gw : gw - NU / 16) * 16;
    const u16* table = isU ? xi16 : xu16;      // gather the OPPOSITE type
    const u16* selfx = isU ? selfU : selfI;
    u16* out         = isU ? outU : outI;
    const u16* wt      = wcat + (isU ? 0 : 64 * 128);
    const float* sc_p  = scsh + (isU ? 0 : 128);
    const float* sh_p  = sc_p + 64;
    int wbase = isU ? node0 : NU + node0;      // unified off/deg index

    // hoist self-path loads: in flight during the whole gather phase
    int row = lane & 15, g = lane >> 4;
    const u16* xrow = selfx + (size_t)(node0 + row) * H + g * 8;
    bf16x8 sa2 = *(const bf16x8*)(xrow);
    bf16x8 sa3 = *(const bf16x8*)(xrow + 32);

    int offv = 0, degv = 0;
    if (lane < 16) { offv = off[wbase + lane]; degv = deg[wbase + lane]; }

    int half = lane >> 5;        // node selector within pair
    int hl   = lane & 31;
    int fl   = hl & 15;          // feature quad: feats fl*4 .. fl*4+3
    int rg   = hl >> 4;          // row group 0..1
    int shb  = (half << 5) + rg; // shuffle base for own node's offsets
    unsigned flb = (unsigned)fl * 8u;          // byte offset within row
    const char* tb = (const char*)table;       // uniform 64-bit base

#define ACC(c) \
    a0  += __uint_as_float((c).x << 16); a1 += __uint_as_float((c).x & 0xFFFF0000u); \
    a2f += __uint_as_float((c).y << 16); a3f += __uint_as_float((c).y & 0xFFFF0000u);

    // ---- phase 1: 8 sequential pair aggregations ----
    for (int p = 0; p < 8; ++p) {
        int begA = __shfl(offv, 2 * p),     dgA = __shfl(degv, 2 * p);
        int begB = __shfl(offv, 2 * p + 1), dgB = __shfl(degv, 2 * p + 1);
        int pd = max((dgA + 7) & ~7, (dgB + 7) & ~7);   // shared padded length
        int myBeg = half ? begB : begA;
        float a0 = 0.f, a1 = 0.f, a2f = 0.f, a3f = 0.f;
        for (int k0 = 0; k0 < pd; k0 += 32) {
            int nb = adj[myBeg + k0 + hl];   // own node's byte offsets
            int lim = min(32, pd - k0);
            unsigned o0 = (unsigned)__shfl(nb, shb + 0) + flb;
            unsigned o1 = (unsigned)__shfl(nb, shb + 2) + flb;
            unsigned o2 = (unsigned)__shfl(nb, shb + 4) + flb;
            unsigned o3 = (unsigned)__shfl(nb, shb + 6) + flb;
            uint2 c0 = *(const uint2*)(tb + o0);
            uint2 c1 = *(const uint2*)(tb + o1);
            uint2 c2 = *(const uint2*)(tb + o2);
            uint2 c3 = *(const uint2*)(tb + o3);
            for (int tt = 8; tt < lim; tt += 8) {
                unsigned q0 = (unsigned)__shfl(nb, shb + tt + 0) + flb;
                unsigned q1 = (unsigned)__shfl(nb, shb + tt + 2) + flb;
                unsigned q2 = (unsigned)__shfl(nb, shb + tt + 4) + flb;
                unsigned q3 = (unsigned)__shfl(nb, shb + tt + 6) + flb;
                uint2 n0 = *(const uint2*)(tb + q0);
                uint2 n1 = *(const uint2*)(tb + q1);
                uint2 n2 = *(const uint2*)(tb + q2);
                uint2 n3 = *(const uint2*)(tb + q3);
                ACC(c0) ACC(c1) ACC(c2) ACC(c3)
                c0 = n0; c1 = n1; c2 = n2; c3 = n3;
            }
            ACC(c0) ACC(c1) ACC(c2) ACC(c3)
        }
        // combine the 2 row-groups of each half
        a0  += __shfl_xor(a0, 16);
        a1  += __shfl_xor(a1, 16);
        a2f += __shfl_xor(a2f, 16);
        a3f += __shfl_xor(a3f, 16);
        int mydg = half ? dgB : dgA;
        if (rg == 0) {   // lanes 0-15 write node 2p; lanes 32-47 write node 2p+1
            float inv = 1.0f / fmaxf((float)mydg, 1.0f);
            unsigned int lo = ((unsigned int)f2bf(a1 * inv) << 16) | f2bf(a0 * inv);
            unsigned int hi = ((unsigned int)f2bf(a3f * inv) << 16) | f2bf(a2f * inv);
            uint2 pk; pk.x = lo; pk.y = hi;
            *(uint2*)&sAgg[wave][2 * p + half][fl * 4] = pk;
        }
    }
#undef ACC
    // no __syncthreads: each wave reads only its own sAgg tile

    // ---- phase 2: MFMA update of the same 16 nodes ----
    bf16x8 a[4];
    a[0] = *(const bf16x8*)&sAgg[wave][row][g * 8];
    a[1] = *(const bf16x8*)&sAgg[wave][row][32 + g * 8];
    a[2] = sa2;
    a[3] = sa3;

#pragma unroll
    for (int ct = 0; ct < 4; ++ct) {
        int feat = ct * 16 + row;
        const u16* wrow = wt + feat * 128 + g * 8;
        f32x4 acc = {0.f, 0.f, 0.f, 0.f};
#pragma unroll
        for (int kb = 0; kb < 4; ++kb) {
            bf16x8 b = *(const bf16x8*)(wrow + kb * 32);
            acc = __builtin_amdgcn_mfma_f32_16x16x32_bf16(a[kb], b, acc, 0, 0, 0);
        }
        float s = sc_p[feat], h = sh_p[feat];
#pragma unroll
        for (int r = 0; r < 4; ++r) {
            int node = node0 + g * 4 + r;   // D: col=lane&15, row=(lane>>4)*4+r
            float v = fmaxf(acc[r] * s + h, 0.f);
            out[(size_t)node * H + feat] = f2bf(v);
        }
    }
}

// ================= MLP head (register-tiled fc1, LDS fc2, bf16 gathers) ========
__global__ __launch_bounds__(256) void mlp_kernel(
    const int* __restrict__ eli,
    const u16* __restrict__ xu16, const u16* __restrict__ xi16,
    const float* __restrict__ fc1w, const float* __restrict__ fc1b,
    const float* __restrict__ fc2w, const float* __restrict__ fc2b,
    float* __restrict__ out, int n)
{
    __shared__ float sW[32][68];
    __shared__ float sA[64][36];
    __shared__ float sH[64][68];
    __shared__ int   sid[128];
    __shared__ float sW2[256];
    int tid = threadIdx.x;
    int p0 = blockIdx.x * 64;
    if (tid < 128) {
        int p = p0 + (tid & 63);
        int side = tid >> 6;
        sid[tid] = (p < n) ? eli[side * NP + p] : -1;
    }
    sW2[tid] = fc2w[tid];
    __syncthreads();

    int jt = (tid & 15) * 4;
    int pt = (tid >> 4) * 4;
    float4 b4 = *(const float4*)&fc1b[jt];
    float acc[4][4];
#pragma unroll
    for (int i = 0; i < 4; ++i) {
        acc[i][0] = b4.x; acc[i][1] = b4.y; acc[i][2] = b4.z; acc[i][3] = b4.w;
    }

    for (int ch = 0; ch < 4; ++ch) {
        int k0 = ch * 32;
        const u16* tab = (ch < 2) ? xu16 : xi16;
        int idbase = (ch < 2) ? 0 : 64;
        int koff = (ch & 1) * 32;
        for (int idx = tid; idx < 64 * 16; idx += 256) {
            int r = idx >> 4, cp = idx & 15;
            int id = sid[idbase + r];
            unsigned int wv = (id >= 0)
                ? *(const unsigned int*)&tab[(size_t)id * H + koff + cp * 2] : 0u;
            sA[r][cp * 2]     = __uint_as_float(wv << 16);
            sA[r][cp * 2 + 1] = __uint_as_float(wv & 0xFFFF0000u);
        }
        for (int idx = tid; idx < 32 * 64; idx += 256) {
            int kk = idx >> 6, j = idx & 63;
            sW[kk][j] = fc1w[(k0 + kk) * 64 + j];
        }
        __syncthreads();
        for (int kk = 0; kk < 32; kk += 4) {
            float a[4][4];
#pragma unroll
            for (int i = 0; i < 4; ++i) {
                float4 t = *(const float4*)&sA[pt + i][kk];
                a[i][0] = t.x; a[i][1] = t.y; a[i][2] = t.z; a[i][3] = t.w;
            }
#pragma unroll
            for (int q = 0; q < 4; ++q) {
                float4 w = *(const float4*)&sW[kk + q][jt];
                float wv[4] = {w.x, w.y, w.z, w.w};
#pragma unroll
                for (int i = 0; i < 4; ++i)
#pragma unroll
                    for (int j = 0; j < 4; ++j)
                        acc[i][j] += a[i][q] * wv[j];
            }
        }
        __syncthreads();
    }

#pragma unroll
    for (int i = 0; i < 4; ++i)
#pragma unroll
        for (int j = 0; j < 4; ++j)
            sH[pt + i][jt + j] = fmaxf(acc[i][j], 0.f);
    __syncthreads();

    int pp = tid >> 2, c = tid & 3;
    float o = 0.f;
#pragma unroll
    for (int j = 0; j < 64; ++j) o += sH[pp][j] * sW2[j * 4 + c];
    int p = p0 + pp;
    if (p < n) out[(size_t)p * 4 + c] = o + fc2b[c];
}

extern "C" void kernel_launch(void* const* d_in, const int* in_sizes, int n_in,
                              void* d_out, int out_size, void* d_ws, size_t ws_size,
                              hipStream_t stream) {
    const int*   edge_index = (const int*)d_in[0];
    const int*   eli        = (const int*)d_in[1];
    const float* user_emb   = (const float*)d_in[2];
    const float* item_emb   = (const float*)d_in[3];
    const float* u_ll_w     = (const float*)d_in[4];
    const float* u_ll_b     = (const float*)d_in[5];
    const float* u_lr_w     = (const float*)d_in[6];
    const float* i_ll_w     = (const float*)d_in[7];
    const float* i_ll_b     = (const float*)d_in[8];
    const float* i_lr_w     = (const float*)d_in[9];
    const float* u_bn_g     = (const float*)d_in[10];
    const float* u_bn_b     = (const float*)d_in[11];
    const float* u_bn_m     = (const float*)d_in[12];
    const float* u_bn_v     = (const float*)d_in[13];
    const float* i_bn_g     = (const float*)d_in[14];
    const float* i_bn_b     = (const float*)d_in[15];
    const float* i_bn_m     = (const float*)d_in[16];
    const float* i_bn_v     = (const float*)d_in[17];
    const float* fc1_w      = (const float*)d_in[18];
    const float* fc1_b      = (const float*)d_in[19];
    const float* fc2_w      = (const float*)d_in[20];
    const float* fc2_b      = (const float*)d_in[21];
    float* out = (float*)d_out;

    const int* src = edge_index;
    const int* dst = edge_index + NE;

    // ---- workspace: 6 slots x 25.6 MB + adj 47.25 MB + off/deg 3.2 MB ≈ 205 MB
    //      (238 MB is the proven-safe ceiling) ----
    const size_t S = (size_t)NROW * H;   // elems per slot (incl. zero row)
    char* w = (char*)d_ws;
    u16* f1 = (u16*)w;          w += 6 * S * 2;
    int* adj    = (int*)w;      w += ((size_t)NB * CAP + 128) * 4;  // +128 overread pad
    int* off    = (int*)w;      w += (size_t)NN * 4;
    int* deg    = (int*)w;      w += (size_t)NN * 4;
    int* g_bcnt = (int*)w;      w += (size_t)NB * 4;
    u16* wcat   = (u16*)w;      w += (size_t)32768 * 2;   // [2][2][64][128] bf16
    float* scsh = (float*)w;    w += (size_t)512 * 4;     // [2][2][2][64] f32

    // Slot plan:
    //   s0/s1: emb16_u/i (prep -> L0 gather + self) -> fin16_u/i (L1 out -> mlp)
    //   s2/s3: staging (47.25 MB spans both; CSR build only)
    //   s4   : blkhist (1.6 MB head; dead after part2)
    //   s4/s5: xA16_u/i (L0 out; L1 gather + self)
    u16* emb16_u = f1 + 0 * S;
    u16* emb16_i = f1 + 1 * S;
    u16* fin16_u = f1 + 0 * S;
    u16* fin16_i = f1 + 1 * S;
    u16* xA16_u  = f1 + 4 * S;
    u16* xA16_i  = f1 + 5 * S;
    int* staging = (int*)(f1 + 2 * S);
    int* blkhist = (int*)(f1 + 4 * S);

    // ---- prep: part1 + cvt + wcvt in one dispatch ----
    prep_kernel<<<PBLOCKS + CVTB + WCVTB, 256, 0, stream>>>(
        src, dst, blkhist,
        (const float4*)user_emb, (const float4*)item_emb,
        (ushort4*)emb16_u, (ushort4*)emb16_i, f1,
        u_ll_w, u_lr_w, i_ll_w, i_lr_w, u_ll_b, i_ll_b,
        u_bn_g, u_bn_b, u_bn_m, u_bn_v,
        i_bn_g, i_bn_b, i_bn_m, i_bn_v, wcat, scsh);

    // ---- CSR build (no global atomics, no memsets, fixed-capacity buckets) ----
    colscan_kernel<<<NB, 256, 0, stream>>>(blkhist, g_bcnt);
    part2_kernel<<<PBLOCKS, 256, 0, stream>>>(src, dst, blkhist, staging);
    bucket_fill_kernel<<<NB, 256, 0, stream>>>(g_bcnt, staging, off, deg, adj);

    const int pu_blocks = (NN / 16) / 4;   // one wave per 16 nodes

    // ---- layer 0 (gather + self both from emb16) ----
    pull_update_kernel<<<pu_blocks, 256, 0, stream>>>(
        off, deg, adj, emb16_u, emb16_i, emb16_u, emb16_i,
        xA16_u, xA16_i, wcat, scsh);

    // ---- layer 1 (gather + self both from xA16) ----
    pull_update_kernel<<<pu_blocks, 256, 0, stream>>>(
        off, deg, adj, xA16_u, xA16_i, xA16_u, xA16_i,
        fin16_u, fin16_i, wcat + 16384, scsh + 256);

    // ---- MLP head ----
    mlp_kernel<<<(NP + 63) / 64, 256, 0, stream>>>(
        eli, fin16_u, fin16_i, fc1_w, fc1_b, fc2_w, fc2_b, out, NP);
}